// Round 9
// baseline (488.447 us; speedup 1.0000x reference)
//
#include <hip/hip_runtime.h>
#include <hip/hip_bf16.h>
#include <cmath>

#define T_ 512
#define B_ 32
#define S_ 512
#define D_ 512
#define NCH 16
#define CT (T_ / NCH)
static constexpr float LN_EPS = 1e-6f;
static constexpr float RSQRT_D = 0.044194173824159216f; // 1/sqrt(512)

typedef __attribute__((ext_vector_type(8))) __bf16 bf16x8;
typedef __attribute__((ext_vector_type(4))) float f32x4;

struct __align__(8) bfx4 { __hip_bfloat16 x, y, z, w; };
struct __align__(16) u16x8 { unsigned short h[8]; };

// ---------------- async global->LDS, 16B per lane ---------------------------
__device__ __forceinline__ void g2l16(const void* g, void* l) {
    __builtin_amdgcn_global_load_lds(
        (const __attribute__((address_space(1))) unsigned int*)g,
        (__attribute__((address_space(3))) unsigned int*)l, 16, 0, 0);
}

// 16-lane xor reductions
__device__ __forceinline__ float xr_sum16(float v) {
    v += __shfl_xor(v, 1); v += __shfl_xor(v, 2);
    v += __shfl_xor(v, 4); v += __shfl_xor(v, 8); return v;
}
__device__ __forceinline__ float xr_max16(float v) {
    v = fmaxf(v, __shfl_xor(v, 1)); v = fmaxf(v, __shfl_xor(v, 2));
    v = fmaxf(v, __shfl_xor(v, 4)); v = fmaxf(v, __shfl_xor(v, 8)); return v;
}

__device__ __forceinline__ float sigmoidf_(float x) {
    return 1.f / (1.f + __expf(-x));
}
__device__ __forceinline__ float sigmoid_fast(float x) {
    return __fdividef(1.f, 1.f + __expf(-x));
}
__device__ __forceinline__ float tanh_fast(float x) {
    return 1.f - __fdividef(2.f, __expf(2.f * x) + 1.f);
}
__device__ __forceinline__ float bfu(unsigned short u) {
    unsigned int v = ((unsigned int)u) << 16;
    return __uint_as_float(v);
}
__device__ __forceinline__ unsigned short f2bu(float f) {
    return __hip_bfloat16_raw(__float2bfloat16(f)).x;
}

// =============== shared 128x128 GEMM body ===================================
// TRIPLE-buffered LDS + counted vmcnt (T4): prefetch 2 K-steps ahead; at each
// step boundary wait vmcnt(4) [= drain the OLDER step's loads, needed next
// step] AND lgkmcnt(0) [= this wave's ds_reads of the current buffer are done,
// so the buffer may be overwritten after the barrier — WAR safety; R8's
// failure was omitting this] + raw s_barrier. This step's 4 loads stay in
// flight ACROSS the barrier. sched_barrier(0) pins next step's ds_read below
// the barrier (rule #18).
__device__ __forceinline__ void g128_body(
    const __hip_bfloat16* __restrict__ A, long ldaE,
    const __hip_bfloat16* __restrict__ Bw,
    __hip_bfloat16* __restrict__ out, long outStrideB,
    float2* __restrict__ part, int partMul, int partBase,
    float scale, int bx, int by)
{
    __shared__ char smem[49152];   // 3 x (A 8KB | B 8KB)
    const int m0 = by * 128, n0 = bx * 128;
    const int tid = threadIdx.x, lane = tid & 63, w = tid >> 6;
    const int wm = (w >> 1) * 64, wn = (w & 1) * 64;
    const int srow = lane >> 2, skB = (lane & 3) * 16;
    const int q = lane >> 4, c = lane & 15;

    f32x4 acc[4][4];
#pragma unroll
    for (int i = 0; i < 4; i++)
#pragma unroll
        for (int j = 0; j < 4; j++) acc[i][j] = (f32x4)(0.0f);

    const char* ga0 = (const char*)(A + (long)(m0 + w * 16 + srow) * ldaE) + skB;
    const char* ga1 = (const char*)(A + (long)(m0 + (w + 4) * 16 + srow) * ldaE) + skB;
    const char* gb0 = (const char*)(Bw + (long)(n0 + w * 16 + srow) * 512) + skB;
    const char* gb1 = (const char*)(Bw + (long)(n0 + (w + 4) * 16 + srow) * 512) + skB;
    char* la0 = smem + w * 1024 + lane * 16;
    char* la1 = smem + (w + 4) * 1024 + lane * 16;
    char* lb0 = smem + 8192 + w * 1024 + lane * 16;
    char* lb1 = smem + 8192 + (w + 4) * 1024 + lane * 16;
    const char* Ar = smem + (wm + c) * 64 + q * 16;
    const char* Br = smem + 8192 + (wn + c) * 64 + q * 16;

    // prologue: stage K-steps 0 and 1 into buffers 0 and 1
    g2l16(ga0, la0);
    g2l16(ga1, la1);
    g2l16(gb0, lb0);
    g2l16(gb1, lb1);
    g2l16(ga0 + 64, la0 + 16384);
    g2l16(ga1 + 64, la1 + 16384);
    g2l16(gb0 + 64, lb0 + 16384);
    g2l16(gb1 + 64, lb1 + 16384);
    asm volatile("s_waitcnt vmcnt(4)" ::: "memory");   // step-0 loads done
    __builtin_amdgcn_s_barrier();
    __builtin_amdgcn_sched_barrier(0);

#pragma unroll
    for (int kk = 0; kk < 16; kk++) {
        const int cb = (kk % 3) * 16384;
        if (kk < 14) {
            const int nb = ((kk + 2) % 3) * 16384;
            const long kb = (long)(kk + 2) * 64;
            g2l16(ga0 + kb, la0 + nb);
            g2l16(ga1 + kb, la1 + nb);
            g2l16(gb0 + kb, lb0 + nb);
            g2l16(gb1 + kb, lb1 + nb);
        }
        bf16x8 af[4], bfr[4];
#pragma unroll
        for (int i = 0; i < 4; i++) {
            af[i] = *(const bf16x8*)(Ar + cb + i * 1024);
            bfr[i] = *(const bf16x8*)(Br + cb + i * 1024);
        }
#pragma unroll
        for (int i = 0; i < 4; i++)
#pragma unroll
            for (int j = 0; j < 4; j++)
                acc[i][j] = __builtin_amdgcn_mfma_f32_16x16x32_bf16(
                    af[i], bfr[j], acc[i][j], 0, 0, 0);
        if (kk < 15) {
            if (kk < 14)
                asm volatile("s_waitcnt vmcnt(4) lgkmcnt(0)" ::: "memory");
            else
                asm volatile("s_waitcnt vmcnt(0) lgkmcnt(0)" ::: "memory");
            __builtin_amdgcn_s_barrier();
            __builtin_amdgcn_sched_barrier(0);
        }
    }
    __syncthreads();   // full drain before smem reuse in epilogue

    if (part) {
        float2* sred = (float2*)smem;    // [128][2]
#pragma unroll
        for (int i = 0; i < 4; i++)
#pragma unroll
            for (int r = 0; r < 4; r++) {
                float s = 0.f, qq = 0.f;
#pragma unroll
                for (int j = 0; j < 4; j++) {
                    float v = acc[i][j][r] * scale; s += v; qq += v * v;
                }
                s = xr_sum16(s); qq = xr_sum16(qq);
                if (c == 0) sred[(wm + i * 16 + q * 4 + r) * 2 + (w & 1)] =
                    make_float2(s, qq);
            }
        __syncthreads();
        if ((w & 1) == 0 && c == 0) {
#pragma unroll
            for (int i = 0; i < 4; i++)
#pragma unroll
                for (int r = 0; r < 4; r++) {
                    int row = wm + i * 16 + q * 4 + r;
                    float2 a = sred[row * 2], b2 = sred[row * 2 + 1];
                    part[(long)bx * 16384 + (long)(m0 + row) * partMul + partBase] =
                        make_float2(a.x + b2.x, a.y + b2.y);
                }
        }
        __syncthreads();
    }

    for (int p = 0; p < 2; p++) {
        if ((w >> 1) == p) {
#pragma unroll
            for (int i = 0; i < 4; i++)
#pragma unroll
                for (int j = 0; j < 4; j++)
#pragma unroll
                    for (int r = 0; r < 4; r++) {
                        int row = i * 16 + q * 4 + r;
                        int col = wn + j * 16 + c;
                        ((__hip_bfloat16*)smem)[row * 128 + col] =
                            __float2bfloat16(acc[i][j][r] * scale);
                    }
        }
        __syncthreads();
#pragma unroll
        for (int rnd = 0; rnd < 4; rnd++) {
            int row = rnd * 16 + (tid >> 4);
            int ch = tid & 15;
            uint4 v = *(const uint4*)(smem + row * 256 + ch * 16);
            long grow = m0 + p * 64 + row;
            *(uint4*)((char*)out + grow * outStrideB + (long)n0 * 2 + ch * 16) = v;
        }
        __syncthreads();
    }
}

// generic wrapper: z-batched or XCD-swizzled 2D
__global__ __launch_bounds__(256) void g128(
    const __hip_bfloat16* __restrict__ A, long ldaE,
    const __hip_bfloat16* __restrict__ Bw, long bStrideZ,
    __hip_bfloat16* __restrict__ out, long outStrideB,
    float2* __restrict__ part, float scale, int swizzle)
{
    int bx, by, pmul = 1, pbase = 0;
    if (gridDim.z > 1) {
        bx = blockIdx.x; by = blockIdx.y;
        A += (long)blockIdx.z * 512;
        Bw += (long)blockIdx.z * bStrideZ;
        out += (long)blockIdx.z * 512;
        pmul = 32; pbase = blockIdx.z;
    } else if (swizzle) {
        const int nwg = gridDim.x * gridDim.y;
        const int lin = blockIdx.y * gridDim.x + blockIdx.x;
        const int cpx = nwg >> 3;
        const int swz = (lin & 7) * cpx + (lin >> 3);
        bx = swz % gridDim.x; by = swz / gridDim.x;
    } else { bx = blockIdx.x; by = blockIdx.y; }
    g128_body(A, ldaE, Bw, out, outStrideB, part, pmul, pbase, scale, bx, by);
}

// =============== merged launch: scan_part1 (512 blocks) + E2 GEMM (1024) ====
__global__ __launch_bounds__(256) void g128e2s(
    const __hip_bfloat16* __restrict__ encb,
    const __hip_bfloat16* __restrict__ WE2,
    __hip_bfloat16* __restrict__ E2, float2* __restrict__ partA,
    const __hip_bfloat16* __restrict__ preb, const float2* __restrict__ stats,
    const float* __restrict__ gpre, const float* __restrict__ bpre,
    float* __restrict__ Ap, float* __restrict__ Bp)
{
    const int bid = blockIdx.x;
    if (bid < 512) {   // ---- scan_part1 role ----
        int i2 = (bid & 31) * 256 + threadIdx.x;   // 0..8191
        int b = i2 >> 8, d = (i2 & 255) * 2;
        int idx = b * 512 + d;
        int ch = bid >> 5;
        float2 gz = *(const float2*)(gpre + d), bz = *(const float2*)(bpre + d);
        float2 gp = *(const float2*)(gpre + 1024 + d);
        float2 bp = *(const float2*)(bpre + 1024 + d);
        float A0 = 1.f, s0 = 0.f, A1 = 1.f, s1 = 0.f;
        for (int t = ch * CT; t < (ch + 1) * CT; t++) {
            long row = (long)t * 32 + b;
            float2 st = stats[row];
            ushort2 zr = *(const ushort2*)(preb + row * 1536 + d);
            ushort2 pr = *(const ushort2*)(preb + row * 1536 + 1024 + d);
            float z0 = sigmoidf_((bfu(zr.x) - st.x) * st.y * gz.x + bz.x);
            float z1 = sigmoidf_((bfu(zr.y) - st.x) * st.y * gz.y + bz.y);
            float p0 = (bfu(pr.x) - st.x) * st.y * gp.x + bp.x;
            float p1 = (bfu(pr.y) - st.x) * st.y * gp.y + bp.y;
            A0 *= (1.f - z0); s0 = (1.f - z0) * s0 + z0 * p0;
            A1 *= (1.f - z1); s1 = (1.f - z1) * s1 + z1 * p1;
        }
        *(float2*)(Ap + ch * 16384 + idx) = make_float2(A0, A1);
        *(float2*)(Bp + ch * 16384 + idx) = make_float2(s0, s1);
        return;
    }
    // ---- E2 GEMM role ----
    const int local = bid - 512;                   // 0..1023
    const int swz = (local & 7) * 128 + (local >> 3);
    g128_body(encb, 512, WE2, E2, 2048, partA, 1, 0, 1.f, swz & 7, swz >> 3);
}

// =============== merged launch: scan_part3 (512) + midfix (8192) ============
__global__ __launch_bounds__(256) void mfix3(
    const __hip_bfloat16* __restrict__ preb, const float2* __restrict__ stats,
    const float* __restrict__ gpre, const float* __restrict__ bpre,
    const float* __restrict__ sinb, __hip_bfloat16* __restrict__ ssb,
    const __hip_bfloat16* __restrict__ E2,
    __hip_bfloat16* __restrict__ pctxb, __hip_bfloat16* __restrict__ pwT,
    const float2* __restrict__ partA,
    const float* __restrict__ g, const float* __restrict__ bb,
    const float* __restrict__ uv)
{
    __shared__ __hip_bfloat16 t[32][34];
    __shared__ float2 sst[32];
    const int bid = blockIdx.x;
    if (bid < 512) {   // ---- scan_part3 role ----
        int i2 = (bid & 31) * 256 + threadIdx.x;
        int b = i2 >> 8, d = (i2 & 255) * 2;
        int idx = b * 512 + d;
        int ch = bid >> 5;
        float2 gz = *(const float2*)(gpre + d), bz = *(const float2*)(bpre + d);
        float2 gp = *(const float2*)(gpre + 1024 + d);
        float2 bp = *(const float2*)(bpre + 1024 + d);
        float2 sv = *(const float2*)(sinb + ch * 16384 + idx);
        float s0 = sv.x, s1 = sv.y;
        for (int tt = ch * CT; tt < (ch + 1) * CT; tt++) {
            long row = (long)tt * 32 + b;
            float2 st = stats[row];
            ushort2 zr = *(const ushort2*)(preb + row * 1536 + d);
            ushort2 pr = *(const ushort2*)(preb + row * 1536 + 1024 + d);
            float z0 = sigmoidf_((bfu(zr.x) - st.x) * st.y * gz.x + bz.x);
            float z1 = sigmoidf_((bfu(zr.y) - st.x) * st.y * gz.y + bz.y);
            float p0 = (bfu(pr.x) - st.x) * st.y * gp.x + bp.x;
            float p1 = (bfu(pr.y) - st.x) * st.y * gp.y + bp.y;
            s0 += z0 * (p0 - s0);
            s1 += z1 * (p1 - s1);
            ushort2 o;
            o.x = f2bu(s0); o.y = f2bu(s1);
            *(ushort2*)(ssb + (long)tt * 16384 + idx) = o;
        }
        return;
    }
    // ---- midfix role (inline stats from partA panels 0-3) ----
    const int local = bid - 512;                   // 0..8191
    const int d0 = (local & 15) * 32;
    const int s0 = ((local >> 4) & 15) * 32;
    const int b = local >> 8;
    if (threadIdx.x < 32) {
        long row = (long)b * 512 + s0 + threadIdx.x;
        float s = 0.f, qq = 0.f;
#pragma unroll
        for (int cb = 0; cb < 4; cb++) {
            float2 v = partA[(long)cb * 16384 + row]; s += v.x; qq += v.y;
        }
        float mn = s * (1.f / 512);
        sst[threadIdx.x] =
            make_float2(mn, rsqrtf(qq * (1.f / 512) - mn * mn + LN_EPS));
    }
    __syncthreads();
    const int tx = threadIdx.x & 31, ty = threadIdx.x >> 5;
    const float gv = g[d0 + tx], bv = bb[d0 + tx];
    const float ud = uv[d0 + tx], vd = uv[512 + d0 + tx];
#pragma unroll
    for (int i = 0; i < 4; i++) {
        int srow = s0 + ty + i * 8;
        long row = (long)b * 512 + srow;
        float2 s = sst[ty + i * 8];
        float pc = __bfloat162float(E2[row * 1024 + d0 + tx]);
        pctxb[row * 512 + d0 + tx] =
            __float2bfloat16((pc - s.x) * s.y * gv + bv);
        float pr = __bfloat162float(E2[row * 1024 + 512 + d0 + tx]);
        t[ty + i * 8][tx] = __float2bfloat16(s.y * pr - s.y * s.x * ud + vd);
    }
    __syncthreads();
#pragma unroll
    for (int i = 0; i < 4; i++)
        pwT[(long)b * 262144 + (long)(d0 + ty + i * 8) * 512 + s0 + tx] =
            t[tx][ty + i * 8];
}

// =============== K4: align GEMM + masked softmax (inline A-side LN) =========
#define RC_BUF 34816
__global__ __launch_bounds__(256, 2) void gemm_attn(
    const __hip_bfloat16* __restrict__ attninC2,   // [16384][1024] RAW cols 0-511
    const __hip_bfloat16* __restrict__ pctxb,
    const float2* __restrict__ partB,              // att panels 0-3
    const float* __restrict__ g_att, const float* __restrict__ b_att,
    const int* __restrict__ mlen,
    float* __restrict__ pattn, __hip_bfloat16* __restrict__ softb)
{
    __shared__ char smem[74240];   // 69632 dbuf | sst 256 | g 2048 | b 2048
    float2* sst = (float2*)(smem + 69632);
    float* gln = (float*)(smem + 69888);
    float* bln = (float*)(smem + 71936);
    const int b = blockIdx.z;
    const long t0 = (long)blockIdx.y * 32;
    const int tid = threadIdx.x, lane = tid & 63, w = tid >> 6;

    // inline LN stats for this block's 32 attn_in rows + g/b preload
    if (tid < 32) {
        long grow = (t0 + tid) * 32 + b;
        float s = 0.f, qq = 0.f;
#pragma unroll
        for (int cb = 0; cb < 4; cb++) {
            float2 v = partB[(long)cb * 16384 + grow]; s += v.x; qq += v.y;
        }
        float mn = s * (1.f / 512);
        sst[tid] = make_float2(mn, rsqrtf(qq * (1.f / 512) - mn * mn + LN_EPS));
    }
    gln[tid] = g_att[tid]; gln[256 + tid] = g_att[256 + tid];
    bln[tid] = b_att[tid]; bln[256 + tid] = b_att[256 + tid];

    // ---- 32-row GEMM core with in-register LN on A fragments ----
    f32x4 acc[2][8];
#pragma unroll
    for (int m = 0; m < 2; m++)
#pragma unroll
        for (int j = 0; j < 8; j++) acc[m][j] = (f32x4)(0.0f);

    const __hip_bfloat16* A = attninC2 + (long)b * 1024 + t0 * 32768;
    const __hip_bfloat16* Bm = pctxb + (long)b * 262144;
    const char* ga = (const char*)(A + (long)(w * 16 + (lane >> 2)) * 32768) + (lane & 3) * 16;
    char* la = smem + w * 1024 + lane * 16;
    const char* gb = (const char*)(Bm + (long)(w * 128 + (lane >> 2)) * 512) + (lane & 3) * 16;
    char* lb = smem + 2048 + w * 8192 + lane * 16;
    const long ldbB16 = 512L * 32;
    const char* Ar = smem + (lane & 15) * 64 + (lane >> 4) * 16;
    const char* Br = smem + 2048 + (w * 128 + (lane & 15)) * 64 + (lane >> 4) * 16;

    if (w < 2) g2l16(ga, la);
#pragma unroll
    for (int s = 0; s < 8; s++) g2l16(gb + s * ldbB16, lb + s * 1024);
    __syncthreads();

    const int fr = lane & 15, kq = lane >> 4;
    const float2 st0 = sst[fr], st1 = sst[16 + fr];

#pragma unroll
    for (int kk = 0; kk < 16; kk++) {
        const int cb = (kk & 1) * RC_BUF;
        const int nb = ((kk & 1) ^ 1) * RC_BUF;
        if (kk < 15) {
            const long kb = (long)(kk + 1) * 64;
            if (w < 2) g2l16(ga + kb, la + nb);
#pragma unroll
            for (int s = 0; s < 8; s++)
                g2l16(gb + kb + s * ldbB16, lb + nb + s * 1024);
        }
        bf16x8 af[2], bfr[8];
#pragma unroll
        for (int m = 0; m < 2; m++) af[m] = *(const bf16x8*)(Ar + cb + m * 1024);
#pragma unroll
        for (int j = 0; j < 8; j++) bfr[j] = *(const bf16x8*)(Br + cb + j * 1024);
        // in-register LN on the two A fragments (k = kk*32 + kq*8 + j)
        {
            const int k0 = kk * 32 + kq * 8;
            float4 gq0 = *(const float4*)(gln + k0);
            float4 gq1 = *(const float4*)(gln + k0 + 4);
            float4 bq0 = *(const float4*)(bln + k0);
            float4 bq1 = *(const float4*)(bln + k0 + 4);
            float gj[8] = {gq0.x, gq0.y, gq0.z, gq0.w, gq1.x, gq1.y, gq1.z, gq1.w};
            float bj[8] = {bq0.x, bq0.y, bq0.z, bq0.w, bq1.x, bq1.y, bq1.z, bq1.w};
            u16x8 u0 = __builtin_bit_cast(u16x8, af[0]);
            u16x8 u1 = __builtin_bit_cast(u16x8, af[1]);
#pragma unroll
            for (int j = 0; j < 8; j++) {
                u0.h[j] = f2bu((bfu(u0.h[j]) - st0.x) * st0.y * gj[j] + bj[j]);
                u1.h[j] = f2bu((bfu(u1.h[j]) - st1.x) * st1.y * gj[j] + bj[j]);
            }
            af[0] = __builtin_bit_cast(bf16x8, u0);
            af[1] = __builtin_bit_cast(bf16x8, u1);
        }
#pragma unroll
        for (int m = 0; m < 2; m++)
#pragma unroll
            for (int j = 0; j < 8; j++)
                acc[m][j] = __builtin_amdgcn_mfma_f32_16x16x32_bf16(
                    af[m], bfr[j], acc[m][j], 0, 0, 0);
        __syncthreads();
    }

    // ---- masked softmax over full 512-wide rows ----
    const int q = lane >> 4, c = lane & 15;
    const int len = mlen[b];
    float* sred = (float*)smem;          // [32][4]

#pragma unroll
    for (int m = 0; m < 2; m++)
#pragma unroll
        for (int r = 0; r < 4; r++) {
            float mx = -INFINITY;
#pragma unroll
            for (int j = 0; j < 8; j++) {
                int col = w * 128 + j * 16 + c;
                float v = acc[m][j][r] * RSQRT_D;
                acc[m][j][r] = v;
                if (col < len) mx = fmaxf(mx, v);
            }
            mx = xr_max16(mx);
            if (c == 0) sred[(m * 16 + q * 4 + r) * 4 + w] = mx;
        }
    __syncthreads();
    float rmax[2][4];
#pragma unroll
    for (int m = 0; m < 2; m++)
#pragma unroll
        for (int r = 0; r < 4; r++) {
            int row = m * 16 + q * 4 + r;
            rmax[m][r] = fmaxf(fmaxf(sred[row * 4], sred[row * 4 + 1]),
                               fmaxf(sred[row * 4 + 2], sred[row * 4 + 3]));
        }
    __syncthreads();
#pragma unroll
    for (int m = 0; m < 2; m++)
#pragma unroll
        for (int r = 0; r < 4; r++) {
            float s = 0.f;
#pragma unroll
            for (int j = 0; j < 8; j++) {
                int col = w * 128 + j * 16 + c;
                float e = (col < len) ? __expf(acc[m][j][r] - rmax[m][r]) : 0.f;
                acc[m][j][r] = e; s += e;
            }
            s = xr_sum16(s);
            if (c == 0) sred[(m * 16 + q * 4 + r) * 4 + w] = s;
        }
    __syncthreads();
    float rinv[2][4];
#pragma unroll
    for (int m = 0; m < 2; m++)
#pragma unroll
        for (int r = 0; r < 4; r++) {
            int row = m * 16 + q * 4 + r;
            rinv[m][r] = 1.f / (sred[row * 4] + sred[row * 4 + 1] +
                                sred[row * 4 + 2] + sred[row * 4 + 3]);
        }
    __syncthreads();

#pragma unroll
    for (int m = 0; m < 2; m++)
#pragma unroll
        for (int j = 0; j < 8; j++)
#pragma unroll
            for (int r = 0; r < 4; r++) {
                int row = m * 16 + q * 4 + r;
                int col = w * 128 + j * 16 + c;
                float p = acc[m][j][r] * rinv[m][r];
                pattn[((t0 + row) * 32 + b) * 512 + col] = p;
                ((__hip_bfloat16*)smem)[row * 512 + col] = __float2bfloat16(p);
            }
    __syncthreads();
#pragma unroll
    for (int rnd = 0; rnd < 8; rnd++) {
        int row = rnd * 4 + w;
        uint4 v = *(const uint4*)(smem + row * 1024 + lane * 16);
        *(uint4*)((char*)softb + ((t0 + row) * 32 + b) * 1024 + lane * 16) = v;
    }
}

// =============== final elementwise fuse (inline stats c,h) ==================
__global__ __launch_bounds__(256) void fin_ep(
    const __hip_bfloat16* __restrict__ h2r,   // [16384][512] (scaled h2)
    const __hip_bfloat16* __restrict__ C2,    // h1raw cols 512+
    const __hip_bfloat16* __restrict__ preb,
    const float2* __restrict__ partC,         // h2 partials, panels 0-3
    const float2* __restrict__ partH,         // h1 partials, panels 0-3
    const float2* __restrict__ st_p,
    const float* __restrict__ g_c, const float* __restrict__ b_c,
    const float* __restrict__ g_h, const float* __restrict__ b_h,
    const float* __restrict__ g_pre, const float* __restrict__ b_pre,
    const float* __restrict__ prev, float* __restrict__ out)
{
    __shared__ float2 shc[32], shh[32];
    const long m0 = (long)blockIdx.x * 32;
    const int tid = threadIdx.x;
    if (tid < 32) {
        long rowg = m0 + tid;
        float s = 0.f, qq = 0.f;
#pragma unroll
        for (int cb = 0; cb < 4; cb++) {
            float2 v = partC[(long)cb * 16384 + rowg]; s += v.x; qq += v.y;
        }
        float mn = s * (1.f / 512);
        shc[tid] = make_float2(mn, rsqrtf(qq * (1.f / 512) - mn * mn + LN_EPS));
    } else if (tid < 64) {
        long rowg = m0 + tid - 32;
        float s = 0.f, qq = 0.f;
#pragma unroll
        for (int cb = 0; cb < 4; cb++) {
            float2 v = partH[(long)cb * 16384 + rowg]; s += v.x; qq += v.y;
        }
        float mn = s * (1.f / 512);
        shh[tid - 32] = make_float2(mn, rsqrtf(qq * (1.f / 512) - mn * mn + LN_EPS));
    }
    __syncthreads();
#pragma unroll
    for (int ch = 0; ch < 16; ch++) {
        int f4 = ch * 256 + tid;             // 0..4095
        int row = f4 >> 7;
        long rowg = m0 + row;
        int col = (f4 & 127) * 4;
        ushort4 h2 = *(const ushort4*)((const char*)h2r + rowg * 1024 + col * 2);
        ushort4 h1 = *(const ushort4*)((const char*)C2 + rowg * 2048 + 1024 + col * 2);
        ushort4 hr = *(const ushort4*)((const char*)preb + rowg * 3072 + 1024 + col * 2);
        float4 pv = *(const float4*)(prev + rowg * 512 + col);
        float4 gc = *(const float4*)(g_c + col), bc = *(const float4*)(b_c + col);
        float4 gh = *(const float4*)(g_h + col), bh = *(const float4*)(b_h + col);
        float4 gp = *(const float4*)(g_pre + 512 + col);
        float4 bp = *(const float4*)(b_pre + 512 + col);
        float2 sc = shc[row], sh = shh[row], sp = st_p[rowg];
        auto fuse = [&](unsigned short h2u, unsigned short h1u, unsigned short hru,
                        float pvv, float gcv, float bcv, float ghv, float bhv,
                        float gpv, float bpv) -> float {
            float t2 = (bfu(h2u) - sc.x) * sc.y * gcv + bcv;
            float t1 = (bfu(h1u) - sh.x) * sh.y * ghv + bhv;
            float hg = sigmoid_fast((bfu(hru) - sp.x) * sp.y * gpv + bpv);
            return (1.f - hg) * tanh_fast(t1 + t2) + hg * pvv;
        };
        float4 o;
        o.x = fuse(h2.x, h1.x, hr.x, pv.x, gc.x, bc.x, gh.x, bh.x, gp.x, bp.x);
        o.y = fuse(h2.y, h1.y, hr.y, pv.y, gc.y, bc.y, gh.y, bh.y, gp.y, bp.y);
        o.z = fuse(h2.z, h1.z, hr.z, pv.z, gc.z, bc.z, gh.z, bh.z, gp.z, bp.z);
        o.w = fuse(h2.w, h1.w, hr.w, pv.w, gc.w, bc.w, gh.w, bh.w, gp.w, bp.w);
        *(float4*)(out + rowg * 512 + col) = o;
    }
}

// =============== small kernels ==============================================
// merged: prev->prevb and enc->encb in one launch
__global__ __launch_bounds__(256) void cvt4d(
    const float* __restrict__ a, __hip_bfloat16* __restrict__ ya,
    const float* __restrict__ b, __hip_bfloat16* __restrict__ yb)
{
    int i = blockIdx.x * 256 + threadIdx.x;     // 0..4194303
    const float* x; __hip_bfloat16* y; int k;
    if (i < 2097152) { x = a; y = ya; k = i; }
    else { x = b; y = yb; k = i - 2097152; }
    float4 v = ((const float4*)x)[k];
    bfx4 o;
    o.x = __float2bfloat16(v.x); o.y = __float2bfloat16(v.y);
    o.z = __float2bfloat16(v.z); o.w = __float2bfloat16(v.w);
    ((bfx4*)y)[k] = o;
}

__global__ __launch_bounds__(256) void wtrans(
    const float* __restrict__ w0, const float* __restrict__ w1,
    const float* __restrict__ w2, const float* __restrict__ w3,
    const float* __restrict__ w4, __hip_bfloat16* __restrict__ WT,
    __hip_bfloat16* __restrict__ WE2)
{
    int z = blockIdx.z;
    const float* W; __hip_bfloat16* O; int N;
    if (z == 0)      { W = w0; O = WT;                          N = 1536; }
    else if (z == 1) { W = w1; O = WE2;                         N = 512; }
    else if (z == 2) { W = w2; O = WT + 786432 + 262144;        N = 512; }
    else if (z == 3) { W = w3; O = WT + 786432 + 524288;        N = 512; }
    else             { W = w4; O = WT + 786432 + 786432;        N = 512; }
    int n0 = blockIdx.x * 32, k0 = blockIdx.y * 32;
    if (n0 >= N) return;
    __shared__ float t[32][33];
    int tx = threadIdx.x & 31, ty = threadIdx.x >> 5;
#pragma unroll
    for (int i = 0; i < 4; i++)
        t[ty + i * 8][tx] = W[(long)(k0 + ty + i * 8) * N + n0 + tx];
    __syncthreads();
#pragma unroll
    for (int i = 0; i < 4; i++)
        O[(long)(n0 + ty + i * 8) * 512 + k0 + tx] =
            __float2bfloat16(t[tx][ty + i * 8]);
}

// merged setup: wgscale (1024 blk) + cvt4(W_enc) (256 blk) + uvk (2 blk)
__global__ __launch_bounds__(256) void wprep(
    const __hip_bfloat16* __restrict__ wctxT, const float* __restrict__ g,
    __hip_bfloat16* __restrict__ wgT,
    const float* __restrict__ Wenc, __hip_bfloat16* __restrict__ wencb,
    const float* __restrict__ Wctx, const float* __restrict__ bvec,
    float* __restrict__ uv)
{
    const int bid = blockIdx.x;
    if (bid < 1024) {          // wgscale
        int i = bid * 256 + threadIdx.x;
        int d1 = i & 511;
        wgT[i] = __float2bfloat16(__bfloat162float(wctxT[i]) * g[d1]);
    } else if (bid < 1280) {   // cvt4 W_enc
        int i = (bid - 1024) * 256 + threadIdx.x;
        float4 v = ((const float4*)Wenc)[i];
        bfx4 o;
        o.x = __float2bfloat16(v.x); o.y = __float2bfloat16(v.y);
        o.z = __float2bfloat16(v.z); o.w = __float2bfloat16(v.w);
        ((bfx4*)wencb)[i] = o;
    } else {                   // uvk
        int d = (bid - 1280) * 256 + threadIdx.x;
        float u = 0.f, v = 0.f;
        for (int k = 0; k < 512; k++) {
            float w = Wctx[(long)k * 512 + d];
            u += g[k] * w; v += bvec[k] * w;
        }
        uv[d] = u; uv[512 + d] = v;
    }
}

__global__ __launch_bounds__(256) void stats_fin(
    const float2* __restrict__ part, float2* __restrict__ stats)
{
    int r = blockIdx.x * 256 + threadIdx.x;
    float s = 0.f, qq = 0.f;
#pragma unroll
    for (int cb = 0; cb < 12; cb++) {
        float2 v = part[(long)cb * 16384 + r]; s += v.x; qq += v.y;
    }
    float m = s * (1.f / 1536);
    float rs = rsqrtf(qq * (1.f / 1536) - m * m + LN_EPS);
    stats[r] = make_float2(m, rs);
}

__global__ __launch_bounds__(256) void scan_part2(
    const float* __restrict__ Ap, const float* __restrict__ Bp,
    const float* __restrict__ h0, float* __restrict__ sin_,
    float* __restrict__ hlast)
{
    int idx = blockIdx.x * 256 + threadIdx.x;
    float s = h0[idx];
    for (int ch = 0; ch < NCH; ch++) {
        sin_[ch * 16384 + idx] = s;
        s = Ap[ch * 16384 + idx] * s + Bp[ch * 16384 + idx];
    }
    hlast[idx] = s;
}

extern "C" void kernel_launch(void* const* d_in, const int* in_sizes, int n_in,
                              void* d_out, int out_size, void* d_ws, size_t ws_size,
                              hipStream_t stream) {
    const float* prev  = (const float*)d_in[0];
    const float* hid0  = (const float*)d_in[1];
    const float* enc   = (const float*)d_in[2];
    const int*   mlen  = (const int*)  d_in[3];
    const float* W_in  = (const float*)d_in[4];
    const float* W_enc = (const float*)d_in[5];
    const float* W_att = (const float*)d_in[6];
    const float* W_hid = (const float*)d_in[7];
    const float* W_ctx = (const float*)d_in[8];
    const float* g_pre = (const float*)d_in[9];
    const float* b_pre = (const float*)d_in[10];
    const float* g_enc = (const float*)d_in[11];
    const float* b_enc = (const float*)d_in[12];
    const float* g_att = (const float*)d_in[13];
    const float* b_att = (const float*)d_in[14];
    const float* g_h   = (const float*)d_in[15];
    const float* b_h   = (const float*)d_in[16];
    const float* g_c   = (const float*)d_in[17];
    const float* b_c   = (const float*)d_in[18];

    float* out   = (float*)d_out;                 // [T,B,D]
    float* hlast = out + (long)T_ * B_ * D_;      // [B,D]
    float* pattn = hlast + (long)B_ * D_;         // [T,B,S]

    char* ws = (char*)d_ws;
    __hip_bfloat16* preb    = (__hip_bfloat16*)(ws);               // 48MB
    __hip_bfloat16* WT      = (__hip_bfloat16*)(ws + 50331648);    // 4MB
    __hip_bfloat16* prevb   = (__hip_bfloat16*)(ws + 54525952);    // 16MB
    __hip_bfloat16* encb    = (__hip_bfloat16*)(ws + 71303168);    // 16MB
    __hip_bfloat16* pctxb   = (__hip_bfloat16*)(ws + 88080384);    // 16MB (LN'd)
    __hip_bfloat16* pwT     = (__hip_bfloat16*)(ws + 104857600);   // 16MB
    __hip_bfloat16* ssb     = (__hip_bfloat16*)(ws + 121634816);   // 16MB
    __hip_bfloat16* C2      = (__hip_bfloat16*)(ws + 138412032);   // 32MB [16384][1024]
    __hip_bfloat16* E2      = (__hip_bfloat16*)(ws + 171966464);   // 32MB [16384][1024]
    __hip_bfloat16* softb   = (__hip_bfloat16*)(ws + 171966464);   // 16MB (E2 lo, dead)
    __hip_bfloat16* h2raw   = (__hip_bfloat16*)(ws + 188743680);   // 16MB (E2 hi, dead)
    float2* part            = (float2*)(ws + 205520896);           // 2MB = 16 panels
    float2* stats           = (float2*)(ws + 207618048);           // 128KB
    float* scanA            = (float*)(ws + 207749120);            // 1MB
    float* scanB            = (float*)(ws + 208797696);            // 1MB
    float* sinb             = (float*)(ws + 209846272);            // 1MB
    __hip_bfloat16* WE2     = (__hip_bfloat16*)(ws + 211419136);   // 1MB [1024][512]
    float* uv               = (float*)(ws + 212467712);            // 4KB
    // setup-phase aliases (dead before scan kernels write them):
    __hip_bfloat16* WgT     = (__hip_bfloat16*)scanA;              // 0.5MB
    __hip_bfloat16* Wencbf  = (__hip_bfloat16*)scanB;              // 0.5MB

    float2* partA = part;                 // E2 panels (0-3 = pctx stats)
    float2* partB = part + 8 * 16384;     // C2 panels (0-3 att | 4-7 h1)
    float2* partC = part;                 // P-GEMM panels (reuse, partA dead)

    const __hip_bfloat16* W_attT = WT + 786432 + 262144;  // [W_att|W_hid] N=1024
    const __hip_bfloat16* W_ctxT = WT + 786432 + 786432;

    dim3 blk(256);

    // ---- setup ----
    cvt4d<<<16384, blk, 0, stream>>>(prev, prevb, enc, encb);
    wtrans<<<dim3(48, 16, 5), blk, 0, stream>>>(W_in, W_enc, W_att, W_hid,
                                                W_ctx, WT, WE2);
    wprep<<<1282, blk, 0, stream>>>(W_ctxT, g_enc, WgT, W_enc, Wencbf,
                                    W_ctx, b_enc, uv);
    g128<<<dim3(4, 4), blk, 0, stream>>>(WgT, 512, Wencbf, 0, WE2 + 262144,
                                         1024, nullptr, 1.f, 0);

    // ---- K1: preact GEMM -> preb bf16 + LN partials (12 panels) ----
    g128<<<dim3(12, 128), blk, 0, stream>>>(prevb, 512, WT, 0, preb, 3072,
                                            part, 1.f, 1);
    stats_fin<<<64, blk, 0, stream>>>(part, stats);

    // ---- merged: scan_part1 (512) + E2 GEMM (1024) ----
    g128e2s<<<1536, blk, 0, stream>>>(encb, WE2, E2, partA, preb, stats,
                                      g_pre, b_pre, scanA, scanB);
    scan_part2<<<64, blk, 0, stream>>>(scanA, scanB, hid0, sinb, hlast);

    // ---- merged: scan_part3 (512) + midfix (8192) ----
    mfix3<<<8704, blk, 0, stream>>>(preb, stats, g_pre, b_pre, sinb, ssb,
                                    E2, pctxb, pwT, partA, g_enc, b_enc, uv);

    // ---- C2 = ss @ [W_att|W_hid] (raw) + partials ----
    g128<<<dim3(8, 128), blk, 0, stream>>>(ssb, 512, W_attT, 0, C2, 2048,
                                           partB, 1.f, 1);

    // ---- K4: align + masked softmax (inline A-LN from partB) ----
    gemm_attn<<<dim3(1, 16, 32), blk, 0, stream>>>(C2, pctxb, partB,
                                                   g_att, b_att, mlen,
                                                   pattn, softb);

    // ---- h2 = P @ pwT / sqrt(d) + partials ----
    g128<<<dim3(4, 4, 32), blk, 0, stream>>>(softb, 16384, pwT, 262144,
                                             h2raw, 32768, partC, RSQRT_D, 0);

    // ---- final fuse (inline stats c,h) ----
    fin_ep<<<512, blk, 0, stream>>>(h2raw, C2, preb, partC,
                                    partB + 4 * 16384, stats,
                                    g_c, b_c, g_h, b_h, g_pre, b_pre, prev,
                                    out);
}

// Round 10
// 421.629 us; speedup vs baseline: 1.1585x; 1.1585x over previous
//
#include <hip/hip_runtime.h>
#include <hip/hip_bf16.h>
#include <cmath>

#define T_ 512
#define B_ 32
#define S_ 512
#define D_ 512
#define NCH 16
#define CT (T_ / NCH)
static constexpr float LN_EPS = 1e-6f;
static constexpr float RSQRT_D = 0.044194173824159216f; // 1/sqrt(512)

typedef __attribute__((ext_vector_type(8))) __bf16 bf16x8;
typedef __attribute__((ext_vector_type(4))) float f32x4;

struct __align__(8) bfx4 { __hip_bfloat16 x, y, z, w; };
struct __align__(16) u16x8 { unsigned short h[8]; };

// ---------------- async global->LDS, 16B per lane ---------------------------
__device__ __forceinline__ void g2l16(const void* g, void* l) {
    __builtin_amdgcn_global_load_lds(
        (const __attribute__((address_space(1))) unsigned int*)g,
        (__attribute__((address_space(3))) unsigned int*)l, 16, 0, 0);
}

// 16-lane xor reductions
__device__ __forceinline__ float xr_sum16(float v) {
    v += __shfl_xor(v, 1); v += __shfl_xor(v, 2);
    v += __shfl_xor(v, 4); v += __shfl_xor(v, 8); return v;
}
__device__ __forceinline__ float xr_max16(float v) {
    v = fmaxf(v, __shfl_xor(v, 1)); v = fmaxf(v, __shfl_xor(v, 2));
    v = fmaxf(v, __shfl_xor(v, 4)); v = fmaxf(v, __shfl_xor(v, 8)); return v;
}

__device__ __forceinline__ float sigmoidf_(float x) {
    return 1.f / (1.f + __expf(-x));
}
__device__ __forceinline__ float sigmoid_fast(float x) {
    return __fdividef(1.f, 1.f + __expf(-x));
}
__device__ __forceinline__ float tanh_fast(float x) {
    return 1.f - __fdividef(2.f, __expf(2.f * x) + 1.f);
}
__device__ __forceinline__ float bfu(unsigned short u) {
    unsigned int v = ((unsigned int)u) << 16;
    return __uint_as_float(v);
}
__device__ __forceinline__ unsigned short f2bu(float f) {
    return __hip_bfloat16_raw(__float2bfloat16(f)).x;
}

// =============== shared 128x128 GEMM body (m97 structure, dbuf) =============
// R10: reverted to the R7 double-buffer + __syncthreads() K-loop. The R8/R9
// triple-buffer counted-vmcnt experiment was null-to-negative at this
// 4-wave 128^2 quadrant (confirms m232's null) and perturbed codegen.
__device__ __forceinline__ void g128_body(
    const __hip_bfloat16* __restrict__ A, long ldaE,
    const __hip_bfloat16* __restrict__ Bw,
    __hip_bfloat16* __restrict__ out, long outStrideB,
    float2* __restrict__ part, int partMul, int partBase,
    float scale, int bx, int by)
{
    __shared__ char smem[32768];   // 2 x (A 8KB | B 8KB)
    const int m0 = by * 128, n0 = bx * 128;
    const int tid = threadIdx.x, lane = tid & 63, w = tid >> 6;
    const int wm = (w >> 1) * 64, wn = (w & 1) * 64;
    const int srow = lane >> 2, skB = (lane & 3) * 16;
    const int q = lane >> 4, c = lane & 15;

    f32x4 acc[4][4];
#pragma unroll
    for (int i = 0; i < 4; i++)
#pragma unroll
        for (int j = 0; j < 4; j++) acc[i][j] = (f32x4)(0.0f);

    const char* ga0 = (const char*)(A + (long)(m0 + w * 16 + srow) * ldaE) + skB;
    const char* ga1 = (const char*)(A + (long)(m0 + (w + 4) * 16 + srow) * ldaE) + skB;
    const char* gb0 = (const char*)(Bw + (long)(n0 + w * 16 + srow) * 512) + skB;
    const char* gb1 = (const char*)(Bw + (long)(n0 + (w + 4) * 16 + srow) * 512) + skB;
    char* la0 = smem + w * 1024 + lane * 16;
    char* la1 = smem + (w + 4) * 1024 + lane * 16;
    char* lb0 = smem + 8192 + w * 1024 + lane * 16;
    char* lb1 = smem + 8192 + (w + 4) * 1024 + lane * 16;
    const char* Ar = smem + (wm + c) * 64 + q * 16;
    const char* Br = smem + 8192 + (wn + c) * 64 + q * 16;

    g2l16(ga0, la0);
    g2l16(ga1, la1);
    g2l16(gb0, lb0);
    g2l16(gb1, lb1);
    __syncthreads();

#pragma unroll
    for (int kk = 0; kk < 16; kk++) {
        const int cb = (kk & 1) << 14;
        const int nb = cb ^ 16384;
        if (kk < 15) {
            const long kb = (long)(kk + 1) * 64;
            g2l16(ga0 + kb, la0 + nb);
            g2l16(ga1 + kb, la1 + nb);
            g2l16(gb0 + kb, lb0 + nb);
            g2l16(gb1 + kb, lb1 + nb);
        }
        bf16x8 af[4], bfr[4];
#pragma unroll
        for (int i = 0; i < 4; i++) {
            af[i] = *(const bf16x8*)(Ar + cb + i * 1024);
            bfr[i] = *(const bf16x8*)(Br + cb + i * 1024);
        }
#pragma unroll
        for (int i = 0; i < 4; i++)
#pragma unroll
            for (int j = 0; j < 4; j++)
                acc[i][j] = __builtin_amdgcn_mfma_f32_16x16x32_bf16(
                    af[i], bfr[j], acc[i][j], 0, 0, 0);
        __syncthreads();
    }

    if (part) {
        float2* sred = (float2*)smem;    // [128][2]
#pragma unroll
        for (int i = 0; i < 4; i++)
#pragma unroll
            for (int r = 0; r < 4; r++) {
                float s = 0.f, qq = 0.f;
#pragma unroll
                for (int j = 0; j < 4; j++) {
                    float v = acc[i][j][r] * scale; s += v; qq += v * v;
                }
                s = xr_sum16(s); qq = xr_sum16(qq);
                if (c == 0) sred[(wm + i * 16 + q * 4 + r) * 2 + (w & 1)] =
                    make_float2(s, qq);
            }
        __syncthreads();
        if ((w & 1) == 0 && c == 0) {
#pragma unroll
            for (int i = 0; i < 4; i++)
#pragma unroll
                for (int r = 0; r < 4; r++) {
                    int row = wm + i * 16 + q * 4 + r;
                    float2 a = sred[row * 2], b2 = sred[row * 2 + 1];
                    part[(long)bx * 16384 + (long)(m0 + row) * partMul + partBase] =
                        make_float2(a.x + b2.x, a.y + b2.y);
                }
        }
        __syncthreads();
    }

    for (int p = 0; p < 2; p++) {
        if ((w >> 1) == p) {
#pragma unroll
            for (int i = 0; i < 4; i++)
#pragma unroll
                for (int j = 0; j < 4; j++)
#pragma unroll
                    for (int r = 0; r < 4; r++) {
                        int row = i * 16 + q * 4 + r;
                        int col = wn + j * 16 + c;
                        ((__hip_bfloat16*)smem)[row * 128 + col] =
                            __float2bfloat16(acc[i][j][r] * scale);
                    }
        }
        __syncthreads();
#pragma unroll
        for (int rnd = 0; rnd < 4; rnd++) {
            int row = rnd * 16 + (tid >> 4);
            int ch = tid & 15;
            uint4 v = *(const uint4*)(smem + row * 256 + ch * 16);
            long grow = m0 + p * 64 + row;
            *(uint4*)((char*)out + grow * outStrideB + (long)n0 * 2 + ch * 16) = v;
        }
        __syncthreads();
    }
}

// generic wrapper: z-batched (with XCD batch-grouping swizzle) or
// XCD-swizzled 2D.
__global__ __launch_bounds__(256) void g128(
    const __hip_bfloat16* __restrict__ A, long ldaE,
    const __hip_bfloat16* __restrict__ Bw, long bStrideZ,
    __hip_bfloat16* __restrict__ out, long outStrideB,
    float2* __restrict__ part, float scale, int swizzle)
{
    int bx, by, pmul = 1, pbase = 0;
    if (gridDim.z > 1) {
        // batch-grouping swizzle: each XCD owns nwg/8 consecutive (z,tile)
        // slots -> per-batch B panels (e.g. pwT[b]) stay in one L2.
        const int bpz = gridDim.x * gridDim.y;
        const int nwg = bpz * gridDim.z;
        const int lin = (blockIdx.z * gridDim.y + blockIdx.y) * gridDim.x
                        + blockIdx.x;
        const int swz = (lin & 7) * (nwg >> 3) + (lin >> 3);
        const int z = swz / bpz, rem = swz % bpz;
        bx = rem % gridDim.x; by = rem / gridDim.x;
        A += (long)z * 512;
        Bw += (long)z * bStrideZ;
        out += (long)z * 512;
        pmul = 32; pbase = z;
    } else if (swizzle) {
        const int nwg = gridDim.x * gridDim.y;
        const int lin = blockIdx.y * gridDim.x + blockIdx.x;
        const int cpx = nwg >> 3;
        const int swz = (lin & 7) * cpx + (lin >> 3);
        bx = swz % gridDim.x; by = swz / gridDim.x;
    } else { bx = blockIdx.x; by = blockIdx.y; }
    g128_body(A, ldaE, Bw, out, outStrideB, part, pmul, pbase, scale, bx, by);
}

// =============== merged launch: scan_part1 (512 blocks) + E2 GEMM (1024) ====
__global__ __launch_bounds__(256) void g128e2s(
    const __hip_bfloat16* __restrict__ encb,
    const __hip_bfloat16* __restrict__ WE2,
    __hip_bfloat16* __restrict__ E2, float2* __restrict__ partA,
    const __hip_bfloat16* __restrict__ preb, const float2* __restrict__ stats,
    const float* __restrict__ gpre, const float* __restrict__ bpre,
    float* __restrict__ Ap, float* __restrict__ Bp)
{
    const int bid = blockIdx.x;
    if (bid < 512) {   // ---- scan_part1 role ----
        int i2 = (bid & 31) * 256 + threadIdx.x;   // 0..8191
        int b = i2 >> 8, d = (i2 & 255) * 2;
        int idx = b * 512 + d;
        int ch = bid >> 5;
        float2 gz = *(const float2*)(gpre + d), bz = *(const float2*)(bpre + d);
        float2 gp = *(const float2*)(gpre + 1024 + d);
        float2 bp = *(const float2*)(bpre + 1024 + d);
        float A0 = 1.f, s0 = 0.f, A1 = 1.f, s1 = 0.f;
        for (int t = ch * CT; t < (ch + 1) * CT; t++) {
            long row = (long)t * 32 + b;
            float2 st = stats[row];
            ushort2 zr = *(const ushort2*)(preb + row * 1536 + d);
            ushort2 pr = *(const ushort2*)(preb + row * 1536 + 1024 + d);
            float z0 = sigmoidf_((bfu(zr.x) - st.x) * st.y * gz.x + bz.x);
            float z1 = sigmoidf_((bfu(zr.y) - st.x) * st.y * gz.y + bz.y);
            float p0 = (bfu(pr.x) - st.x) * st.y * gp.x + bp.x;
            float p1 = (bfu(pr.y) - st.x) * st.y * gp.y + bp.y;
            A0 *= (1.f - z0); s0 = (1.f - z0) * s0 + z0 * p0;
            A1 *= (1.f - z1); s1 = (1.f - z1) * s1 + z1 * p1;
        }
        *(float2*)(Ap + ch * 16384 + idx) = make_float2(A0, A1);
        *(float2*)(Bp + ch * 16384 + idx) = make_float2(s0, s1);
        return;
    }
    // ---- E2 GEMM role ----
    const int local = bid - 512;                   // 0..1023
    const int swz = (local & 7) * 128 + (local >> 3);
    g128_body(encb, 512, WE2, E2, 2048, partA, 1, 0, 1.f, swz & 7, swz >> 3);
}

// =============== merged launch: scan_part3 (512) + midfix (8192) ============
__global__ __launch_bounds__(256) void mfix3(
    const __hip_bfloat16* __restrict__ preb, const float2* __restrict__ stats,
    const float* __restrict__ gpre, const float* __restrict__ bpre,
    const float* __restrict__ sinb, __hip_bfloat16* __restrict__ ssb,
    const __hip_bfloat16* __restrict__ E2,
    __hip_bfloat16* __restrict__ pctxb, __hip_bfloat16* __restrict__ pwT,
    const float2* __restrict__ partA,
    const float* __restrict__ g, const float* __restrict__ bb,
    const float* __restrict__ uv)
{
    __shared__ __hip_bfloat16 t[32][34];
    __shared__ float2 sst[32];
    const int bid = blockIdx.x;
    if (bid < 512) {   // ---- scan_part3 role ----
        int i2 = (bid & 31) * 256 + threadIdx.x;
        int b = i2 >> 8, d = (i2 & 255) * 2;
        int idx = b * 512 + d;
        int ch = bid >> 5;
        float2 gz = *(const float2*)(gpre + d), bz = *(const float2*)(bpre + d);
        float2 gp = *(const float2*)(gpre + 1024 + d);
        float2 bp = *(const float2*)(bpre + 1024 + d);
        float2 sv = *(const float2*)(sinb + ch * 16384 + idx);
        float s0 = sv.x, s1 = sv.y;
        for (int tt = ch * CT; tt < (ch + 1) * CT; tt++) {
            long row = (long)tt * 32 + b;
            float2 st = stats[row];
            ushort2 zr = *(const ushort2*)(preb + row * 1536 + d);
            ushort2 pr = *(const ushort2*)(preb + row * 1536 + 1024 + d);
            float z0 = sigmoidf_((bfu(zr.x) - st.x) * st.y * gz.x + bz.x);
            float z1 = sigmoidf_((bfu(zr.y) - st.x) * st.y * gz.y + bz.y);
            float p0 = (bfu(pr.x) - st.x) * st.y * gp.x + bp.x;
            float p1 = (bfu(pr.y) - st.x) * st.y * gp.y + bp.y;
            s0 += z0 * (p0 - s0);
            s1 += z1 * (p1 - s1);
            ushort2 o;
            o.x = f2bu(s0); o.y = f2bu(s1);
            *(ushort2*)(ssb + (long)tt * 16384 + idx) = o;
        }
        return;
    }
    // ---- midfix role (inline stats from partA panels 0-3) ----
    const int local = bid - 512;                   // 0..8191
    const int d0 = (local & 15) * 32;
    const int s0 = ((local >> 4) & 15) * 32;
    const int b = local >> 8;
    if (threadIdx.x < 32) {
        long row = (long)b * 512 + s0 + threadIdx.x;
        float s = 0.f, qq = 0.f;
#pragma unroll
        for (int cb = 0; cb < 4; cb++) {
            float2 v = partA[(long)cb * 16384 + row]; s += v.x; qq += v.y;
        }
        float mn = s * (1.f / 512);
        sst[threadIdx.x] =
            make_float2(mn, rsqrtf(qq * (1.f / 512) - mn * mn + LN_EPS));
    }
    __syncthreads();
    const int tx = threadIdx.x & 31, ty = threadIdx.x >> 5;
    const float gv = g[d0 + tx], bv = bb[d0 + tx];
    const float ud = uv[d0 + tx], vd = uv[512 + d0 + tx];
#pragma unroll
    for (int i = 0; i < 4; i++) {
        int srow = s0 + ty + i * 8;
        long row = (long)b * 512 + srow;
        float2 s = sst[ty + i * 8];
        float pc = __bfloat162float(E2[row * 1024 + d0 + tx]);
        pctxb[row * 512 + d0 + tx] =
            __float2bfloat16((pc - s.x) * s.y * gv + bv);
        float pr = __bfloat162float(E2[row * 1024 + 512 + d0 + tx]);
        t[ty + i * 8][tx] = __float2bfloat16(s.y * pr - s.y * s.x * ud + vd);
    }
    __syncthreads();
#pragma unroll
    for (int i = 0; i < 4; i++)
        pwT[(long)b * 262144 + (long)(d0 + ty + i * 8) * 512 + s0 + tx] =
            t[tx][ty + i * 8];
}

// =============== K4: align GEMM + masked softmax (inline A-side LN) =========
// Batch-grouping XCD swizzle: lin = z*16+y; each XCD owns 4 complete batches
// -> each batch's 512KB pctx panel is fetched by ONE L2 instead of all 8.
#define RC_BUF 34816
__global__ __launch_bounds__(256, 2) void gemm_attn(
    const __hip_bfloat16* __restrict__ attninC2,   // [16384][1024] RAW cols 0-511
    const __hip_bfloat16* __restrict__ pctxb,
    const float2* __restrict__ partB,              // att panels 0-3
    const float* __restrict__ g_att, const float* __restrict__ b_att,
    const int* __restrict__ mlen,
    float* __restrict__ pattn, __hip_bfloat16* __restrict__ softb)
{
    __shared__ char smem[74240];   // 69632 dbuf | sst 256 | g 2048 | b 2048
    float2* sst = (float2*)(smem + 69632);
    float* gln = (float*)(smem + 69888);
    float* bln = (float*)(smem + 71936);
    const int lin = blockIdx.z * 16 + blockIdx.y;  // 0..511
    const int swzb = (lin & 7) * 64 + (lin >> 3);  // XCD-contiguous
    const int b = swzb >> 4;
    const long t0 = (long)(swzb & 15) * 32;
    const int tid = threadIdx.x, lane = tid & 63, w = tid >> 6;

    // inline LN stats for this block's 32 attn_in rows + g/b preload
    if (tid < 32) {
        long grow = (t0 + tid) * 32 + b;
        float s = 0.f, qq = 0.f;
#pragma unroll
        for (int cb = 0; cb < 4; cb++) {
            float2 v = partB[(long)cb * 16384 + grow]; s += v.x; qq += v.y;
        }
        float mn = s * (1.f / 512);
        sst[tid] = make_float2(mn, rsqrtf(qq * (1.f / 512) - mn * mn + LN_EPS));
    }
    gln[tid] = g_att[tid]; gln[256 + tid] = g_att[256 + tid];
    bln[tid] = b_att[tid]; bln[256 + tid] = b_att[256 + tid];

    // ---- 32-row GEMM core with in-register LN on A fragments ----
    f32x4 acc[2][8];
#pragma unroll
    for (int m = 0; m < 2; m++)
#pragma unroll
        for (int j = 0; j < 8; j++) acc[m][j] = (f32x4)(0.0f);

    const __hip_bfloat16* A = attninC2 + (long)b * 1024 + t0 * 32768;
    const __hip_bfloat16* Bm = pctxb + (long)b * 262144;
    const char* ga = (const char*)(A + (long)(w * 16 + (lane >> 2)) * 32768) + (lane & 3) * 16;
    char* la = smem + w * 1024 + lane * 16;
    const char* gb = (const char*)(Bm + (long)(w * 128 + (lane >> 2)) * 512) + (lane & 3) * 16;
    char* lb = smem + 2048 + w * 8192 + lane * 16;
    const long ldbB16 = 512L * 32;
    const char* Ar = smem + (lane & 15) * 64 + (lane >> 4) * 16;
    const char* Br = smem + 2048 + (w * 128 + (lane & 15)) * 64 + (lane >> 4) * 16;

    if (w < 2) g2l16(ga, la);
#pragma unroll
    for (int s = 0; s < 8; s++) g2l16(gb + s * ldbB16, lb + s * 1024);
    __syncthreads();

    const int fr = lane & 15, kq = lane >> 4;
    const float2 st0 = sst[fr], st1 = sst[16 + fr];

#pragma unroll
    for (int kk = 0; kk < 16; kk++) {
        const int cb = (kk & 1) * RC_BUF;
        const int nb = ((kk & 1) ^ 1) * RC_BUF;
        if (kk < 15) {
            const long kb = (long)(kk + 1) * 64;
            if (w < 2) g2l16(ga + kb, la + nb);
#pragma unroll
            for (int s = 0; s < 8; s++)
                g2l16(gb + kb + s * ldbB16, lb + nb + s * 1024);
        }
        bf16x8 af[2], bfr[8];
#pragma unroll
        for (int m = 0; m < 2; m++) af[m] = *(const bf16x8*)(Ar + cb + m * 1024);
#pragma unroll
        for (int j = 0; j < 8; j++) bfr[j] = *(const bf16x8*)(Br + cb + j * 1024);
        // in-register LN on the two A fragments (k = kk*32 + kq*8 + j)
        {
            const int k0 = kk * 32 + kq * 8;
            float4 gq0 = *(const float4*)(gln + k0);
            float4 gq1 = *(const float4*)(gln + k0 + 4);
            float4 bq0 = *(const float4*)(bln + k0);
            float4 bq1 = *(const float4*)(bln + k0 + 4);
            float gj[8] = {gq0.x, gq0.y, gq0.z, gq0.w, gq1.x, gq1.y, gq1.z, gq1.w};
            float bj[8] = {bq0.x, bq0.y, bq0.z, bq0.w, bq1.x, bq1.y, bq1.z, bq1.w};
            u16x8 u0 = __builtin_bit_cast(u16x8, af[0]);
            u16x8 u1 = __builtin_bit_cast(u16x8, af[1]);
#pragma unroll
            for (int j = 0; j < 8; j++) {
                u0.h[j] = f2bu((bfu(u0.h[j]) - st0.x) * st0.y * gj[j] + bj[j]);
                u1.h[j] = f2bu((bfu(u1.h[j]) - st1.x) * st1.y * gj[j] + bj[j]);
            }
            af[0] = __builtin_bit_cast(bf16x8, u0);
            af[1] = __builtin_bit_cast(bf16x8, u1);
        }
#pragma unroll
        for (int m = 0; m < 2; m++)
#pragma unroll
            for (int j = 0; j < 8; j++)
                acc[m][j] = __builtin_amdgcn_mfma_f32_16x16x32_bf16(
                    af[m], bfr[j], acc[m][j], 0, 0, 0);
        __syncthreads();
    }

    // ---- masked softmax over full 512-wide rows ----
    const int q = lane >> 4, c = lane & 15;
    const int len = mlen[b];
    float* sred = (float*)smem;          // [32][4]

#pragma unroll
    for (int m = 0; m < 2; m++)
#pragma unroll
        for (int r = 0; r < 4; r++) {
            float mx = -INFINITY;
#pragma unroll
            for (int j = 0; j < 8; j++) {
                int col = w * 128 + j * 16 + c;
                float v = acc[m][j][r] * RSQRT_D;
                acc[m][j][r] = v;
                if (col < len) mx = fmaxf(mx, v);
            }
            mx = xr_max16(mx);
            if (c == 0) sred[(m * 16 + q * 4 + r) * 4 + w] = mx;
        }
    __syncthreads();
    float rmax[2][4];
#pragma unroll
    for (int m = 0; m < 2; m++)
#pragma unroll
        for (int r = 0; r < 4; r++) {
            int row = m * 16 + q * 4 + r;
            rmax[m][r] = fmaxf(fmaxf(sred[row * 4], sred[row * 4 + 1]),
                               fmaxf(sred[row * 4 + 2], sred[row * 4 + 3]));
        }
    __syncthreads();
#pragma unroll
    for (int m = 0; m < 2; m++)
#pragma unroll
        for (int r = 0; r < 4; r++) {
            float s = 0.f;
#pragma unroll
            for (int j = 0; j < 8; j++) {
                int col = w * 128 + j * 16 + c;
                float e = (col < len) ? __expf(acc[m][j][r] - rmax[m][r]) : 0.f;
                acc[m][j][r] = e; s += e;
            }
            s = xr_sum16(s);
            if (c == 0) sred[(m * 16 + q * 4 + r) * 4 + w] = s;
        }
    __syncthreads();
    float rinv[2][4];
#pragma unroll
    for (int m = 0; m < 2; m++)
#pragma unroll
        for (int r = 0; r < 4; r++) {
            int row = m * 16 + q * 4 + r;
            rinv[m][r] = 1.f / (sred[row * 4] + sred[row * 4 + 1] +
                                sred[row * 4 + 2] + sred[row * 4 + 3]);
        }
    __syncthreads();

#pragma unroll
    for (int m = 0; m < 2; m++)
#pragma unroll
        for (int j = 0; j < 8; j++)
#pragma unroll
            for (int r = 0; r < 4; r++) {
                int row = m * 16 + q * 4 + r;
                int col = w * 128 + j * 16 + c;
                float p = acc[m][j][r] * rinv[m][r];
                pattn[((t0 + row) * 32 + b) * 512 + col] = p;
                ((__hip_bfloat16*)smem)[row * 512 + col] = __float2bfloat16(p);
            }
    __syncthreads();
#pragma unroll
    for (int rnd = 0; rnd < 8; rnd++) {
        int row = rnd * 4 + w;
        uint4 v = *(const uint4*)(smem + row * 1024 + lane * 16);
        *(uint4*)((char*)softb + ((t0 + row) * 32 + b) * 1024 + lane * 16) = v;
    }
}

// =============== final elementwise fuse (inline stats c,h) ==================
__global__ __launch_bounds__(256) void fin_ep(
    const __hip_bfloat16* __restrict__ h2r,   // [16384][512] (scaled h2)
    const __hip_bfloat16* __restrict__ C2,    // h1raw cols 512+
    const __hip_bfloat16* __restrict__ preb,
    const float2* __restrict__ partC,         // h2 partials, panels 0-3
    const float2* __restrict__ partH,         // h1 partials, panels 0-3
    const float2* __restrict__ st_p,
    const float* __restrict__ g_c, const float* __restrict__ b_c,
    const float* __restrict__ g_h, const float* __restrict__ b_h,
    const float* __restrict__ g_pre, const float* __restrict__ b_pre,
    const float* __restrict__ prev, float* __restrict__ out)
{
    __shared__ float2 shc[32], shh[32];
    const long m0 = (long)blockIdx.x * 32;
    const int tid = threadIdx.x;
    if (tid < 32) {
        long rowg = m0 + tid;
        float s = 0.f, qq = 0.f;
#pragma unroll
        for (int cb = 0; cb < 4; cb++) {
            float2 v = partC[(long)cb * 16384 + rowg]; s += v.x; qq += v.y;
        }
        float mn = s * (1.f / 512);
        shc[tid] = make_float2(mn, rsqrtf(qq * (1.f / 512) - mn * mn + LN_EPS));
    } else if (tid < 64) {
        long rowg = m0 + tid - 32;
        float s = 0.f, qq = 0.f;
#pragma unroll
        for (int cb = 0; cb < 4; cb++) {
            float2 v = partH[(long)cb * 16384 + rowg]; s += v.x; qq += v.y;
        }
        float mn = s * (1.f / 512);
        shh[tid - 32] = make_float2(mn, rsqrtf(qq * (1.f / 512) - mn * mn + LN_EPS));
    }
    __syncthreads();
#pragma unroll
    for (int ch = 0; ch < 16; ch++) {
        int f4 = ch * 256 + tid;             // 0..4095
        int row = f4 >> 7;
        long rowg = m0 + row;
        int col = (f4 & 127) * 4;
        ushort4 h2 = *(const ushort4*)((const char*)h2r + rowg * 1024 + col * 2);
        ushort4 h1 = *(const ushort4*)((const char*)C2 + rowg * 2048 + 1024 + col * 2);
        ushort4 hr = *(const ushort4*)((const char*)preb + rowg * 3072 + 1024 + col * 2);
        float4 pv = *(const float4*)(prev + rowg * 512 + col);
        float4 gc = *(const float4*)(g_c + col), bc = *(const float4*)(b_c + col);
        float4 gh = *(const float4*)(g_h + col), bh = *(const float4*)(b_h + col);
        float4 gp = *(const float4*)(g_pre + 512 + col);
        float4 bp = *(const float4*)(b_pre + 512 + col);
        float2 sc = shc[row], sh = shh[row], sp = st_p[rowg];
        auto fuse = [&](unsigned short h2u, unsigned short h1u, unsigned short hru,
                        float pvv, float gcv, float bcv, float ghv, float bhv,
                        float gpv, float bpv) -> float {
            float t2 = (bfu(h2u) - sc.x) * sc.y * gcv + bcv;
            float t1 = (bfu(h1u) - sh.x) * sh.y * ghv + bhv;
            float hg = sigmoid_fast((bfu(hru) - sp.x) * sp.y * gpv + bpv);
            return (1.f - hg) * tanh_fast(t1 + t2) + hg * pvv;
        };
        float4 o;
        o.x = fuse(h2.x, h1.x, hr.x, pv.x, gc.x, bc.x, gh.x, bh.x, gp.x, bp.x);
        o.y = fuse(h2.y, h1.y, hr.y, pv.y, gc.y, bc.y, gh.y, bh.y, gp.y, bp.y);
        o.z = fuse(h2.z, h1.z, hr.z, pv.z, gc.z, bc.z, gh.z, bh.z, gp.z, bp.z);
        o.w = fuse(h2.w, h1.w, hr.w, pv.w, gc.w, bc.w, gh.w, bh.w, gp.w, bp.w);
        *(float4*)(out + rowg * 512 + col) = o;
    }
}

// =============== small kernels ==============================================
// merged: prev->prevb and enc->encb in one launch
__global__ __launch_bounds__(256) void cvt4d(
    const float* __restrict__ a, __hip_bfloat16* __restrict__ ya,
    const float* __restrict__ b, __hip_bfloat16* __restrict__ yb)
{
    int i = blockIdx.x * 256 + threadIdx.x;     // 0..4194303
    const float* x; __hip_bfloat16* y; int k;
    if (i < 2097152) { x = a; y = ya; k = i; }
    else { x = b; y = yb; k = i - 2097152; }
    float4 v = ((const float4*)x)[k];
    bfx4 o;
    o.x = __float2bfloat16(v.x); o.y = __float2bfloat16(v.y);
    o.z = __float2bfloat16(v.z); o.w = __float2bfloat16(v.w);
    ((bfx4*)y)[k] = o;
}

__global__ __launch_bounds__(256) void wtrans(
    const float* __restrict__ w0, const float* __restrict__ w1,
    const float* __restrict__ w2, const float* __restrict__ w3,
    const float* __restrict__ w4, __hip_bfloat16* __restrict__ WT,
    __hip_bfloat16* __restrict__ WE2)
{
    int z = blockIdx.z;
    const float* W; __hip_bfloat16* O; int N;
    if (z == 0)      { W = w0; O = WT;                          N = 1536; }
    else if (z == 1) { W = w1; O = WE2;                         N = 512; }
    else if (z == 2) { W = w2; O = WT + 786432 + 262144;        N = 512; }
    else if (z == 3) { W = w3; O = WT + 786432 + 524288;        N = 512; }
    else             { W = w4; O = WT + 786432 + 786432;        N = 512; }
    int n0 = blockIdx.x * 32, k0 = blockIdx.y * 32;
    if (n0 >= N) return;
    __shared__ float t[32][33];
    int tx = threadIdx.x & 31, ty = threadIdx.x >> 5;
#pragma unroll
    for (int i = 0; i < 4; i++)
        t[ty + i * 8][tx] = W[(long)(k0 + ty + i * 8) * N + n0 + tx];
    __syncthreads();
#pragma unroll
    for (int i = 0; i < 4; i++)
        O[(long)(n0 + ty + i * 8) * 512 + k0 + tx] =
            __float2bfloat16(t[tx][ty + i * 8]);
}

// merged setup: wgscale (1024 blk) + cvt4(W_enc) (256 blk) + uvk (2 blk)
__global__ __launch_bounds__(256) void wprep(
    const __hip_bfloat16* __restrict__ wctxT, const float* __restrict__ g,
    __hip_bfloat16* __restrict__ wgT,
    const float* __restrict__ Wenc, __hip_bfloat16* __restrict__ wencb,
    const float* __restrict__ Wctx, const float* __restrict__ bvec,
    float* __restrict__ uv)
{
    const int bid = blockIdx.x;
    if (bid < 1024) {          // wgscale
        int i = bid * 256 + threadIdx.x;
        int d1 = i & 511;
        wgT[i] = __float2bfloat16(__bfloat162float(wctxT[i]) * g[d1]);
    } else if (bid < 1280) {   // cvt4 W_enc
        int i = (bid - 1024) * 256 + threadIdx.x;
        float4 v = ((const float4*)Wenc)[i];
        bfx4 o;
        o.x = __float2bfloat16(v.x); o.y = __float2bfloat16(v.y);
        o.z = __float2bfloat16(v.z); o.w = __float2bfloat16(v.w);
        ((bfx4*)wencb)[i] = o;
    } else {                   // uvk
        int d = (bid - 1280) * 256 + threadIdx.x;
        float u = 0.f, v = 0.f;
        for (int k = 0; k < 512; k++) {
            float w = Wctx[(long)k * 512 + d];
            u += g[k] * w; v += bvec[k] * w;
        }
        uv[d] = u; uv[512 + d] = v;
    }
}

__global__ __launch_bounds__(256) void stats_fin(
    const float2* __restrict__ part, float2* __restrict__ stats)
{
    int r = blockIdx.x * 256 + threadIdx.x;
    float s = 0.f, qq = 0.f;
#pragma unroll
    for (int cb = 0; cb < 12; cb++) {
        float2 v = part[(long)cb * 16384 + r]; s += v.x; qq += v.y;
    }
    float m = s * (1.f / 1536);
    float rs = rsqrtf(qq * (1.f / 1536) - m * m + LN_EPS);
    stats[r] = make_float2(m, rs);
}

__global__ __launch_bounds__(256) void scan_part2(
    const float* __restrict__ Ap, const float* __restrict__ Bp,
    const float* __restrict__ h0, float* __restrict__ sin_,
    float* __restrict__ hlast)
{
    int idx = blockIdx.x * 256 + threadIdx.x;
    float s = h0[idx];
    for (int ch = 0; ch < NCH; ch++) {
        sin_[ch * 16384 + idx] = s;
        s = Ap[ch * 16384 + idx] * s + Bp[ch * 16384 + idx];
    }
    hlast[idx] = s;
}

extern "C" void kernel_launch(void* const* d_in, const int* in_sizes, int n_in,
                              void* d_out, int out_size, void* d_ws, size_t ws_size,
                              hipStream_t stream) {
    const float* prev  = (const float*)d_in[0];
    const float* hid0  = (const float*)d_in[1];
    const float* enc   = (const float*)d_in[2];
    const int*   mlen  = (const int*)  d_in[3];
    const float* W_in  = (const float*)d_in[4];
    const float* W_enc = (const float*)d_in[5];
    const float* W_att = (const float*)d_in[6];
    const float* W_hid = (const float*)d_in[7];
    const float* W_ctx = (const float*)d_in[8];
    const float* g_pre = (const float*)d_in[9];
    const float* b_pre = (const float*)d_in[10];
    const float* g_enc = (const float*)d_in[11];
    const float* b_enc = (const float*)d_in[12];
    const float* g_att = (const float*)d_in[13];
    const float* b_att = (const float*)d_in[14];
    const float* g_h   = (const float*)d_in[15];
    const float* b_h   = (const float*)d_in[16];
    const float* g_c   = (const float*)d_in[17];
    const float* b_c   = (const float*)d_in[18];

    float* out   = (float*)d_out;                 // [T,B,D]
    float* hlast = out + (long)T_ * B_ * D_;      // [B,D]
    float* pattn = hlast + (long)B_ * D_;         // [T,B,S]

    char* ws = (char*)d_ws;
    __hip_bfloat16* preb    = (__hip_bfloat16*)(ws);               // 48MB
    __hip_bfloat16* WT      = (__hip_bfloat16*)(ws + 50331648);    // 4MB
    __hip_bfloat16* prevb   = (__hip_bfloat16*)(ws + 54525952);    // 16MB
    __hip_bfloat16* encb    = (__hip_bfloat16*)(ws + 71303168);    // 16MB
    __hip_bfloat16* pctxb   = (__hip_bfloat16*)(ws + 88080384);    // 16MB (LN'd)
    __hip_bfloat16* pwT     = (__hip_bfloat16*)(ws + 104857600);   // 16MB
    __hip_bfloat16* ssb     = (__hip_bfloat16*)(ws + 121634816);   // 16MB
    __hip_bfloat16* C2      = (__hip_bfloat16*)(ws + 138412032);   // 32MB [16384][1024]
    __hip_bfloat16* E2      = (__hip_bfloat16*)(ws + 171966464);   // 32MB [16384][1024]
    __hip_bfloat16* softb   = (__hip_bfloat16*)(ws + 171966464);   // 16MB (E2 lo, dead)
    __hip_bfloat16* h2raw   = (__hip_bfloat16*)(ws + 188743680);   // 16MB (E2 hi, dead)
    float2* part            = (float2*)(ws + 205520896);           // 2MB = 16 panels
    float2* stats           = (float2*)(ws + 207618048);           // 128KB
    float* scanA            = (float*)(ws + 207749120);            // 1MB
    float* scanB            = (float*)(ws + 208797696);            // 1MB
    float* sinb             = (float*)(ws + 209846272);            // 1MB
    __hip_bfloat16* WE2     = (__hip_bfloat16*)(ws + 211419136);   // 1MB [1024][512]
    float* uv               = (float*)(ws + 212467712);            // 4KB
    // setup-phase aliases (dead before scan kernels write them):
    __hip_bfloat16* WgT     = (__hip_bfloat16*)scanA;              // 0.5MB
    __hip_bfloat16* Wencbf  = (__hip_bfloat16*)scanB;              // 0.5MB

    float2* partA = part;                 // E2 panels (0-3 = pctx stats)
    float2* partB = part + 8 * 16384;     // C2 panels (0-3 att | 4-7 h1)
    float2* partC = part;                 // P-GEMM panels (reuse, partA dead)

    const __hip_bfloat16* W_attT = WT + 786432 + 262144;  // [W_att|W_hid] N=1024
    const __hip_bfloat16* W_ctxT = WT + 786432 + 786432;

    dim3 blk(256);

    // ---- setup ----
    cvt4d<<<16384, blk, 0, stream>>>(prev, prevb, enc, encb);
    wtrans<<<dim3(48, 16, 5), blk, 0, stream>>>(W_in, W_enc, W_att, W_hid,
                                                W_ctx, WT, WE2);
    wprep<<<1282, blk, 0, stream>>>(W_ctxT, g_enc, WgT, W_enc, Wencbf,
                                    W_ctx, b_enc, uv);
    g128<<<dim3(4, 4), blk, 0, stream>>>(WgT, 512, Wencbf, 0, WE2 + 262144,
                                         1024, nullptr, 1.f, 0);

    // ---- K1: preact GEMM -> preb bf16 + LN partials (12 panels) ----
    g128<<<dim3(12, 128), blk, 0, stream>>>(prevb, 512, WT, 0, preb, 3072,
                                            part, 1.f, 1);
    stats_fin<<<64, blk, 0, stream>>>(part, stats);

    // ---- merged: scan_part1 (512) + E2 GEMM (1024) ----
    g128e2s<<<1536, blk, 0, stream>>>(encb, WE2, E2, partA, preb, stats,
                                      g_pre, b_pre, scanA, scanB);
    scan_part2<<<64, blk, 0, stream>>>(scanA, scanB, hid0, sinb, hlast);

    // ---- merged: scan_part3 (512) + midfix (8192) ----
    mfix3<<<8704, blk, 0, stream>>>(preb, stats, g_pre, b_pre, sinb, ssb,
                                    E2, pctxb, pwT, partA, g_enc, b_enc, uv);

    // ---- C2 = ss @ [W_att|W_hid] (raw) + partials ----
    g128<<<dim3(8, 128), blk, 0, stream>>>(ssb, 512, W_attT, 0, C2, 2048,
                                           partB, 1.f, 1);

    // ---- K4: align + masked softmax (inline A-LN, XCD batch swizzle) ----
    gemm_attn<<<dim3(1, 16, 32), blk, 0, stream>>>(C2, pctxb, partB,
                                                   g_att, b_att, mlen,
                                                   pattn, softb);

    // ---- h2 = P @ pwT / sqrt(d) + partials (XCD batch swizzle) ----
    g128<<<dim3(4, 4, 32), blk, 0, stream>>>(softb, 16384, pwT, 262144,
                                             h2raw, 32768, partC, RSQRT_D, 0);

    // ---- final fuse (inline stats c,h) ----
    fin_ep<<<512, blk, 0, stream>>>(h2raw, C2, preb, partC,
                                    partB + 4 * 16384, stats,
                                    g_c, b_c, g_h, b_h, g_pre, b_pre, prev,
                                    out);
}

// Round 11
// 411.608 us; speedup vs baseline: 1.1867x; 1.0243x over previous
//
#include <hip/hip_runtime.h>
#include <hip/hip_bf16.h>
#include <cmath>

#define T_ 512
#define B_ 32
#define S_ 512
#define D_ 512
#define NCH 16
#define CT (T_ / NCH)
static constexpr float LN_EPS = 1e-6f;
static constexpr float RSQRT_D = 0.044194173824159216f; // 1/sqrt(512)

typedef __attribute__((ext_vector_type(8))) __bf16 bf16x8;
typedef __attribute__((ext_vector_type(4))) float f32x4;

struct __align__(8) bfx4 { __hip_bfloat16 x, y, z, w; };
struct __align__(16) u16x8 { unsigned short h[8]; };

// ---------------- async global->LDS, 16B per lane ---------------------------
__device__ __forceinline__ void g2l16(const void* g, void* l) {
    __builtin_amdgcn_global_load_lds(
        (const __attribute__((address_space(1))) unsigned int*)g,
        (__attribute__((address_space(3))) unsigned int*)l, 16, 0, 0);
}

// 16-lane xor reductions
__device__ __forceinline__ float xr_sum16(float v) {
    v += __shfl_xor(v, 1); v += __shfl_xor(v, 2);
    v += __shfl_xor(v, 4); v += __shfl_xor(v, 8); return v;
}
__device__ __forceinline__ float xr_max16(float v) {
    v = fmaxf(v, __shfl_xor(v, 1)); v = fmaxf(v, __shfl_xor(v, 2));
    v = fmaxf(v, __shfl_xor(v, 4)); v = fmaxf(v, __shfl_xor(v, 8)); return v;
}

__device__ __forceinline__ float sigmoidf_(float x) {
    return 1.f / (1.f + __expf(-x));
}
__device__ __forceinline__ float sigmoid_fast(float x) {
    return __fdividef(1.f, 1.f + __expf(-x));
}
__device__ __forceinline__ float tanh_fast(float x) {
    return 1.f - __fdividef(2.f, __expf(2.f * x) + 1.f);
}
__device__ __forceinline__ float bfu(unsigned short u) {
    unsigned int v = ((unsigned int)u) << 16;
    return __uint_as_float(v);
}
__device__ __forceinline__ unsigned short f2bu(float f) {
    return __hip_bfloat16_raw(__float2bfloat16(f)).x;
}

// =============== shared 128x128 GEMM body (m97 structure, dbuf) =============
__device__ __forceinline__ void g128_body(
    const __hip_bfloat16* __restrict__ A, long ldaE,
    const __hip_bfloat16* __restrict__ Bw,
    __hip_bfloat16* __restrict__ out, long outStrideB,
    float2* __restrict__ part, int partMul, int partBase,
    float scale, int bx, int by)
{
    __shared__ char smem[32768];   // 2 x (A 8KB | B 8KB)
    const int m0 = by * 128, n0 = bx * 128;
    const int tid = threadIdx.x, lane = tid & 63, w = tid >> 6;
    const int wm = (w >> 1) * 64, wn = (w & 1) * 64;
    const int srow = lane >> 2, skB = (lane & 3) * 16;
    const int q = lane >> 4, c = lane & 15;

    f32x4 acc[4][4];
#pragma unroll
    for (int i = 0; i < 4; i++)
#pragma unroll
        for (int j = 0; j < 4; j++) acc[i][j] = (f32x4)(0.0f);

    const char* ga0 = (const char*)(A + (long)(m0 + w * 16 + srow) * ldaE) + skB;
    const char* ga1 = (const char*)(A + (long)(m0 + (w + 4) * 16 + srow) * ldaE) + skB;
    const char* gb0 = (const char*)(Bw + (long)(n0 + w * 16 + srow) * 512) + skB;
    const char* gb1 = (const char*)(Bw + (long)(n0 + (w + 4) * 16 + srow) * 512) + skB;
    char* la0 = smem + w * 1024 + lane * 16;
    char* la1 = smem + (w + 4) * 1024 + lane * 16;
    char* lb0 = smem + 8192 + w * 1024 + lane * 16;
    char* lb1 = smem + 8192 + (w + 4) * 1024 + lane * 16;
    const char* Ar = smem + (wm + c) * 64 + q * 16;
    const char* Br = smem + 8192 + (wn + c) * 64 + q * 16;

    g2l16(ga0, la0);
    g2l16(ga1, la1);
    g2l16(gb0, lb0);
    g2l16(gb1, lb1);
    __syncthreads();

#pragma unroll
    for (int kk = 0; kk < 16; kk++) {
        const int cb = (kk & 1) << 14;
        const int nb = cb ^ 16384;
        if (kk < 15) {
            const long kb = (long)(kk + 1) * 64;
            g2l16(ga0 + kb, la0 + nb);
            g2l16(ga1 + kb, la1 + nb);
            g2l16(gb0 + kb, lb0 + nb);
            g2l16(gb1 + kb, lb1 + nb);
        }
        bf16x8 af[4], bfr[4];
#pragma unroll
        for (int i = 0; i < 4; i++) {
            af[i] = *(const bf16x8*)(Ar + cb + i * 1024);
            bfr[i] = *(const bf16x8*)(Br + cb + i * 1024);
        }
#pragma unroll
        for (int i = 0; i < 4; i++)
#pragma unroll
            for (int j = 0; j < 4; j++)
                acc[i][j] = __builtin_amdgcn_mfma_f32_16x16x32_bf16(
                    af[i], bfr[j], acc[i][j], 0, 0, 0);
        __syncthreads();
    }

    if (part) {
        float2* sred = (float2*)smem;    // [128][2]
#pragma unroll
        for (int i = 0; i < 4; i++)
#pragma unroll
            for (int r = 0; r < 4; r++) {
                float s = 0.f, qq = 0.f;
#pragma unroll
                for (int j = 0; j < 4; j++) {
                    float v = acc[i][j][r] * scale; s += v; qq += v * v;
                }
                s = xr_sum16(s); qq = xr_sum16(qq);
                if (c == 0) sred[(wm + i * 16 + q * 4 + r) * 2 + (w & 1)] =
                    make_float2(s, qq);
            }
        __syncthreads();
        if ((w & 1) == 0 && c == 0) {
#pragma unroll
            for (int i = 0; i < 4; i++)
#pragma unroll
                for (int r = 0; r < 4; r++) {
                    int row = wm + i * 16 + q * 4 + r;
                    float2 a = sred[row * 2], b2 = sred[row * 2 + 1];
                    part[(long)bx * 16384 + (long)(m0 + row) * partMul + partBase] =
                        make_float2(a.x + b2.x, a.y + b2.y);
                }
        }
        __syncthreads();
    }

    for (int p = 0; p < 2; p++) {
        if ((w >> 1) == p) {
#pragma unroll
            for (int i = 0; i < 4; i++)
#pragma unroll
                for (int j = 0; j < 4; j++)
#pragma unroll
                    for (int r = 0; r < 4; r++) {
                        int row = i * 16 + q * 4 + r;
                        int col = wn + j * 16 + c;
                        ((__hip_bfloat16*)smem)[row * 128 + col] =
                            __float2bfloat16(acc[i][j][r] * scale);
                    }
        }
        __syncthreads();
#pragma unroll
        for (int rnd = 0; rnd < 4; rnd++) {
            int row = rnd * 16 + (tid >> 4);
            int ch = tid & 15;
            uint4 v = *(const uint4*)(smem + row * 256 + ch * 16);
            long grow = m0 + p * 64 + row;
            *(uint4*)((char*)out + grow * outStrideB + (long)n0 * 2 + ch * 16) = v;
        }
        __syncthreads();
    }
}

// generic wrapper: z-batched (with XCD batch-grouping swizzle) or
// XCD-swizzled 2D.
__global__ __launch_bounds__(256) void g128(
    const __hip_bfloat16* __restrict__ A, long ldaE,
    const __hip_bfloat16* __restrict__ Bw, long bStrideZ,
    __hip_bfloat16* __restrict__ out, long outStrideB,
    float2* __restrict__ part, float scale, int swizzle)
{
    int bx, by, pmul = 1, pbase = 0;
    if (gridDim.z > 1) {
        // batch-grouping swizzle: each XCD owns nwg/8 consecutive (z,tile)
        // slots -> per-batch B panels (e.g. pwT[b]) stay in one L2.
        const int bpz = gridDim.x * gridDim.y;
        const int nwg = bpz * gridDim.z;
        const int lin = (blockIdx.z * gridDim.y + blockIdx.y) * gridDim.x
                        + blockIdx.x;
        const int swz = (lin & 7) * (nwg >> 3) + (lin >> 3);
        const int z = swz / bpz, rem = swz % bpz;
        bx = rem % gridDim.x; by = rem / gridDim.x;
        A += (long)z * 512;
        Bw += (long)z * bStrideZ;
        out += (long)z * 512;
        pmul = 32; pbase = z;
    } else if (swizzle) {
        const int nwg = gridDim.x * gridDim.y;
        const int lin = blockIdx.y * gridDim.x + blockIdx.x;
        const int cpx = nwg >> 3;
        const int swz = (lin & 7) * cpx + (lin >> 3);
        bx = swz % gridDim.x; by = swz / gridDim.x;
    } else { bx = blockIdx.x; by = blockIdx.y; }
    g128_body(A, ldaE, Bw, out, outStrideB, part, pmul, pbase, scale, bx, by);
}

// =============== merged launch: scan_part1 (512 blocks) + E2 GEMM (1024) ====
__global__ __launch_bounds__(256) void g128e2s(
    const __hip_bfloat16* __restrict__ encb,
    const __hip_bfloat16* __restrict__ WE2,
    __hip_bfloat16* __restrict__ E2, float2* __restrict__ partA,
    const __hip_bfloat16* __restrict__ preb, const float2* __restrict__ stats,
    const float* __restrict__ gpre, const float* __restrict__ bpre,
    float* __restrict__ Ap, float* __restrict__ Bp)
{
    const int bid = blockIdx.x;
    if (bid < 512) {   // ---- scan_part1 role ----
        int i2 = (bid & 31) * 256 + threadIdx.x;   // 0..8191
        int b = i2 >> 8, d = (i2 & 255) * 2;
        int idx = b * 512 + d;
        int ch = bid >> 5;
        float2 gz = *(const float2*)(gpre + d), bz = *(const float2*)(bpre + d);
        float2 gp = *(const float2*)(gpre + 1024 + d);
        float2 bp = *(const float2*)(bpre + 1024 + d);
        float A0 = 1.f, s0 = 0.f, A1 = 1.f, s1 = 0.f;
        for (int t = ch * CT; t < (ch + 1) * CT; t++) {
            long row = (long)t * 32 + b;
            float2 st = stats[row];
            ushort2 zr = *(const ushort2*)(preb + row * 1536 + d);
            ushort2 pr = *(const ushort2*)(preb + row * 1536 + 1024 + d);
            float z0 = sigmoidf_((bfu(zr.x) - st.x) * st.y * gz.x + bz.x);
            float z1 = sigmoidf_((bfu(zr.y) - st.x) * st.y * gz.y + bz.y);
            float p0 = (bfu(pr.x) - st.x) * st.y * gp.x + bp.x;
            float p1 = (bfu(pr.y) - st.x) * st.y * gp.y + bp.y;
            A0 *= (1.f - z0); s0 = (1.f - z0) * s0 + z0 * p0;
            A1 *= (1.f - z1); s1 = (1.f - z1) * s1 + z1 * p1;
        }
        *(float2*)(Ap + ch * 16384 + idx) = make_float2(A0, A1);
        *(float2*)(Bp + ch * 16384 + idx) = make_float2(s0, s1);
        return;
    }
    // ---- E2 GEMM role ----
    const int local = bid - 512;                   // 0..1023
    const int swz = (local & 7) * 128 + (local >> 3);
    g128_body(encb, 512, WE2, E2, 2048, partA, 1, 0, 1.f, swz & 7, swz >> 3);
}

// =============== merged launch: scan_part3 (512) + midfix (8192) ============
__global__ __launch_bounds__(256) void mfix3(
    const __hip_bfloat16* __restrict__ preb, const float2* __restrict__ stats,
    const float* __restrict__ gpre, const float* __restrict__ bpre,
    const float* __restrict__ sinb, __hip_bfloat16* __restrict__ ssb,
    const __hip_bfloat16* __restrict__ E2,
    __hip_bfloat16* __restrict__ pctxb, __hip_bfloat16* __restrict__ pwT,
    const float2* __restrict__ partA,
    const float* __restrict__ g, const float* __restrict__ bb,
    const float* __restrict__ uv)
{
    __shared__ __hip_bfloat16 t[32][34];
    __shared__ float2 sst[32];
    const int bid = blockIdx.x;
    if (bid < 512) {   // ---- scan_part3 role ----
        int i2 = (bid & 31) * 256 + threadIdx.x;
        int b = i2 >> 8, d = (i2 & 255) * 2;
        int idx = b * 512 + d;
        int ch = bid >> 5;
        float2 gz = *(const float2*)(gpre + d), bz = *(const float2*)(bpre + d);
        float2 gp = *(const float2*)(gpre + 1024 + d);
        float2 bp = *(const float2*)(bpre + 1024 + d);
        float2 sv = *(const float2*)(sinb + ch * 16384 + idx);
        float s0 = sv.x, s1 = sv.y;
        for (int tt = ch * CT; tt < (ch + 1) * CT; tt++) {
            long row = (long)tt * 32 + b;
            float2 st = stats[row];
            ushort2 zr = *(const ushort2*)(preb + row * 1536 + d);
            ushort2 pr = *(const ushort2*)(preb + row * 1536 + 1024 + d);
            float z0 = sigmoidf_((bfu(zr.x) - st.x) * st.y * gz.x + bz.x);
            float z1 = sigmoidf_((bfu(zr.y) - st.x) * st.y * gz.y + bz.y);
            float p0 = (bfu(pr.x) - st.x) * st.y * gp.x + bp.x;
            float p1 = (bfu(pr.y) - st.x) * st.y * gp.y + bp.y;
            s0 += z0 * (p0 - s0);
            s1 += z1 * (p1 - s1);
            ushort2 o;
            o.x = f2bu(s0); o.y = f2bu(s1);
            *(ushort2*)(ssb + (long)tt * 16384 + idx) = o;
        }
        return;
    }
    // ---- midfix role (inline stats from partA panels 0-3) ----
    const int local = bid - 512;                   // 0..8191
    const int d0 = (local & 15) * 32;
    const int s0 = ((local >> 4) & 15) * 32;
    const int b = local >> 8;
    if (threadIdx.x < 32) {
        long row = (long)b * 512 + s0 + threadIdx.x;
        float s = 0.f, qq = 0.f;
#pragma unroll
        for (int cb = 0; cb < 4; cb++) {
            float2 v = partA[(long)cb * 16384 + row]; s += v.x; qq += v.y;
        }
        float mn = s * (1.f / 512);
        sst[threadIdx.x] =
            make_float2(mn, rsqrtf(qq * (1.f / 512) - mn * mn + LN_EPS));
    }
    __syncthreads();
    const int tx = threadIdx.x & 31, ty = threadIdx.x >> 5;
    const float gv = g[d0 + tx], bv = bb[d0 + tx];
    const float ud = uv[d0 + tx], vd = uv[512 + d0 + tx];
#pragma unroll
    for (int i = 0; i < 4; i++) {
        int srow = s0 + ty + i * 8;
        long row = (long)b * 512 + srow;
        float2 s = sst[ty + i * 8];
        float pc = __bfloat162float(E2[row * 1024 + d0 + tx]);
        pctxb[row * 512 + d0 + tx] =
            __float2bfloat16((pc - s.x) * s.y * gv + bv);
        float pr = __bfloat162float(E2[row * 1024 + 512 + d0 + tx]);
        t[ty + i * 8][tx] = __float2bfloat16(s.y * pr - s.y * s.x * ud + vd);
    }
    __syncthreads();
#pragma unroll
    for (int i = 0; i < 4; i++)
        pwT[(long)b * 262144 + (long)(d0 + ty + i * 8) * 512 + s0 + tx] =
            t[tx][ty + i * 8];
}

// =============== K4: align GEMM + masked softmax (64 rows, 8 waves) =========
// 512-thread blocks, 2 row-groups x 4 col-quadrant waves. The B tile (pctx,
// 32KB/step dbuf) is staged ONCE and consumed by both row-groups -> half the
// B re-stage traffic (8 vs 16 blocks/batch) and 16 waves/CU (vs 8).
// Batch-grouping XCD swizzle: each XCD owns 4 complete batches.
#define AT_BUF 36864    // per dbuf buffer: A 2x2KB | B 32KB
__global__ __launch_bounds__(512, 1) void gemm_attn(
    const __hip_bfloat16* __restrict__ attninC2,   // [16384][1024] RAW cols 0-511
    const __hip_bfloat16* __restrict__ pctxb,
    const float2* __restrict__ partB,              // att panels 0-3
    const float* __restrict__ g_att, const float* __restrict__ b_att,
    const int* __restrict__ mlen,
    float* __restrict__ pattn, __hip_bfloat16* __restrict__ softb)
{
    __shared__ char smem[78336];   // 2xAT_BUF | sst 512 | g 2048 | b 2048
    float2* sst = (float2*)(smem + 73728);
    float* gln = (float*)(smem + 74240);
    float* bln = (float*)(smem + 76288);
    const int lin = blockIdx.z * 8 + blockIdx.y;   // 0..255
    const int swzb = (lin & 7) * 32 + (lin >> 3);  // XCD-contiguous
    const int b = swzb >> 3;
    const long t0 = (long)(swzb & 7) * 64;         // 64-row base
    const int tid = threadIdx.x, lane = tid & 63, w = tid >> 6;
    const int wg = w >> 2;          // row-group 0/1
    const int wq = w & 3;           // col quadrant

    // inline LN stats for this block's 64 attn_in rows + g/b preload
    if (tid < 64) {
        long grow = (t0 + tid) * 32 + b;
        float s = 0.f, qq = 0.f;
#pragma unroll
        for (int cb = 0; cb < 4; cb++) {
            float2 v = partB[(long)cb * 16384 + grow]; s += v.x; qq += v.y;
        }
        float mn = s * (1.f / 512);
        sst[tid] = make_float2(mn, rsqrtf(qq * (1.f / 512) - mn * mn + LN_EPS));
    }
    if (tid < 256) {
        gln[tid] = g_att[tid]; gln[256 + tid] = g_att[256 + tid];
        bln[tid] = b_att[tid]; bln[256 + tid] = b_att[256 + tid];
    }

    // ---- 64-row GEMM core with in-register LN on A fragments ----
    f32x4 acc[2][8];
#pragma unroll
    for (int m = 0; m < 2; m++)
#pragma unroll
        for (int j = 0; j < 8; j++) acc[m][j] = (f32x4)(0.0f);

    const __hip_bfloat16* A = attninC2 + (long)b * 1024 + t0 * 32768;
    const __hip_bfloat16* Bm = pctxb + (long)b * 262144;
    // A staging: waves {0,1} stage group0 rows 0-31, waves {4,5} group1 32-63
    const int awl = w & 3;          // 0..3 within group
    const char* ga = (const char*)(A + (long)(wg * 32 + awl * 16 + (lane >> 2)) * 32768)
                     + (lane & 3) * 16;
    char* la = smem + wg * 2048 + awl * 1024 + lane * 16;
    const int doA = (awl < 2);
    // B staging: 32 chunks of 16 rows; wave w stages chunks w*4..w*4+3
    const char* gb = (const char*)(Bm + (long)(w * 64 + (lane >> 2)) * 512) + (lane & 3) * 16;
    char* lb = smem + 4096 + w * 4096 + lane * 16;
    const long ldbB16 = 512L * 32;   // 16 B-rows in bytes
    const char* Ar = smem + wg * 2048 + (lane & 15) * 64 + (lane >> 4) * 16;
    const char* Br = smem + 4096 + (wq * 128 + (lane & 15)) * 64 + (lane >> 4) * 16;

    if (doA) g2l16(ga, la);
#pragma unroll
    for (int s = 0; s < 4; s++) g2l16(gb + s * ldbB16, lb + s * 1024);
    __syncthreads();

    const int fr = lane & 15, kq = lane >> 4;
    const float2 st0 = sst[wg * 32 + fr], st1 = sst[wg * 32 + 16 + fr];

#pragma unroll
    for (int kk = 0; kk < 16; kk++) {
        const int cb = (kk & 1) * AT_BUF;
        const int nb = ((kk & 1) ^ 1) * AT_BUF;
        if (kk < 15) {
            const long kb = (long)(kk + 1) * 64;
            if (doA) g2l16(ga + kb, la + nb);
#pragma unroll
            for (int s = 0; s < 4; s++)
                g2l16(gb + kb + s * ldbB16, lb + nb + s * 1024);
        }
        bf16x8 af[2], bfr[8];
#pragma unroll
        for (int m = 0; m < 2; m++) af[m] = *(const bf16x8*)(Ar + cb + m * 1024);
#pragma unroll
        for (int j = 0; j < 8; j++) bfr[j] = *(const bf16x8*)(Br + cb + j * 1024);
        // in-register LN on the two A fragments (k = kk*32 + kq*8 + j)
        {
            const int k0 = kk * 32 + kq * 8;
            float4 gq0 = *(const float4*)(gln + k0);
            float4 gq1 = *(const float4*)(gln + k0 + 4);
            float4 bq0 = *(const float4*)(bln + k0);
            float4 bq1 = *(const float4*)(bln + k0 + 4);
            float gj[8] = {gq0.x, gq0.y, gq0.z, gq0.w, gq1.x, gq1.y, gq1.z, gq1.w};
            float bj[8] = {bq0.x, bq0.y, bq0.z, bq0.w, bq1.x, bq1.y, bq1.z, bq1.w};
            u16x8 u0 = __builtin_bit_cast(u16x8, af[0]);
            u16x8 u1 = __builtin_bit_cast(u16x8, af[1]);
#pragma unroll
            for (int j = 0; j < 8; j++) {
                u0.h[j] = f2bu((bfu(u0.h[j]) - st0.x) * st0.y * gj[j] + bj[j]);
                u1.h[j] = f2bu((bfu(u1.h[j]) - st1.x) * st1.y * gj[j] + bj[j]);
            }
            af[0] = __builtin_bit_cast(bf16x8, u0);
            af[1] = __builtin_bit_cast(bf16x8, u1);
        }
#pragma unroll
        for (int m = 0; m < 2; m++)
#pragma unroll
            for (int j = 0; j < 8; j++)
                acc[m][j] = __builtin_amdgcn_mfma_f32_16x16x32_bf16(
                    af[m], bfr[j], acc[m][j], 0, 0, 0);
        __syncthreads();
    }

    // ---- masked softmax over full 512-wide rows (64 rows) ----
    const int q = lane >> 4, c = lane & 15;
    const int len = mlen[b];
    float* sred = (float*)smem;          // [64][4]
    const int rb = wg * 32;              // row base for this wave's group

#pragma unroll
    for (int m = 0; m < 2; m++)
#pragma unroll
        for (int r = 0; r < 4; r++) {
            float mx = -INFINITY;
#pragma unroll
            for (int j = 0; j < 8; j++) {
                int col = wq * 128 + j * 16 + c;
                float v = acc[m][j][r] * RSQRT_D;
                acc[m][j][r] = v;
                if (col < len) mx = fmaxf(mx, v);
            }
            mx = xr_max16(mx);
            if (c == 0) sred[(rb + m * 16 + q * 4 + r) * 4 + wq] = mx;
        }
    __syncthreads();
    float rmax[2][4];
#pragma unroll
    for (int m = 0; m < 2; m++)
#pragma unroll
        for (int r = 0; r < 4; r++) {
            int row = rb + m * 16 + q * 4 + r;
            rmax[m][r] = fmaxf(fmaxf(sred[row * 4], sred[row * 4 + 1]),
                               fmaxf(sred[row * 4 + 2], sred[row * 4 + 3]));
        }
    __syncthreads();
#pragma unroll
    for (int m = 0; m < 2; m++)
#pragma unroll
        for (int r = 0; r < 4; r++) {
            float s = 0.f;
#pragma unroll
            for (int j = 0; j < 8; j++) {
                int col = wq * 128 + j * 16 + c;
                float e = (col < len) ? __expf(acc[m][j][r] - rmax[m][r]) : 0.f;
                acc[m][j][r] = e; s += e;
            }
            s = xr_sum16(s);
            if (c == 0) sred[(rb + m * 16 + q * 4 + r) * 4 + wq] = s;
        }
    __syncthreads();
    float rinv[2][4];
#pragma unroll
    for (int m = 0; m < 2; m++)
#pragma unroll
        for (int r = 0; r < 4; r++) {
            int row = rb + m * 16 + q * 4 + r;
            rinv[m][r] = 1.f / (sred[row * 4] + sred[row * 4 + 1] +
                                sred[row * 4 + 2] + sred[row * 4 + 3]);
        }
    __syncthreads();

#pragma unroll
    for (int m = 0; m < 2; m++)
#pragma unroll
        for (int j = 0; j < 8; j++)
#pragma unroll
            for (int r = 0; r < 4; r++) {
                int row = rb + m * 16 + q * 4 + r;
                int col = wq * 128 + j * 16 + c;
                float p = acc[m][j][r] * rinv[m][r];
                pattn[((t0 + row) * 32 + b) * 512 + col] = p;
                ((__hip_bfloat16*)smem)[row * 512 + col] = __float2bfloat16(p);
            }
    __syncthreads();
#pragma unroll
    for (int rnd = 0; rnd < 8; rnd++) {
        int row = rnd * 8 + (tid >> 6);
        uint4 v = *(const uint4*)(smem + row * 1024 + lane * 16);
        *(uint4*)((char*)softb + ((t0 + row) * 32 + b) * 1024 + lane * 16) = v;
    }
}

// =============== final elementwise fuse (inline stats c,h) ==================
__global__ __launch_bounds__(256) void fin_ep(
    const __hip_bfloat16* __restrict__ h2r,   // [16384][512] (scaled h2)
    const __hip_bfloat16* __restrict__ C2,    // h1raw cols 512+
    const __hip_bfloat16* __restrict__ preb,
    const float2* __restrict__ partC,         // h2 partials, panels 0-3
    const float2* __restrict__ partH,         // h1 partials, panels 0-3
    const float2* __restrict__ st_p,
    const float* __restrict__ g_c, const float* __restrict__ b_c,
    const float* __restrict__ g_h, const float* __restrict__ b_h,
    const float* __restrict__ g_pre, const float* __restrict__ b_pre,
    const float* __restrict__ prev, float* __restrict__ out)
{
    __shared__ float2 shc[32], shh[32];
    const long m0 = (long)blockIdx.x * 32;
    const int tid = threadIdx.x;
    if (tid < 32) {
        long rowg = m0 + tid;
        float s = 0.f, qq = 0.f;
#pragma unroll
        for (int cb = 0; cb < 4; cb++) {
            float2 v = partC[(long)cb * 16384 + rowg]; s += v.x; qq += v.y;
        }
        float mn = s * (1.f / 512);
        shc[tid] = make_float2(mn, rsqrtf(qq * (1.f / 512) - mn * mn + LN_EPS));
    } else if (tid < 64) {
        long rowg = m0 + tid - 32;
        float s = 0.f, qq = 0.f;
#pragma unroll
        for (int cb = 0; cb < 4; cb++) {
            float2 v = partH[(long)cb * 16384 + rowg]; s += v.x; qq += v.y;
        }
        float mn = s * (1.f / 512);
        shh[tid - 32] = make_float2(mn, rsqrtf(qq * (1.f / 512) - mn * mn + LN_EPS));
    }
    __syncthreads();
#pragma unroll
    for (int ch = 0; ch < 16; ch++) {
        int f4 = ch * 256 + tid;             // 0..4095
        int row = f4 >> 7;
        long rowg = m0 + row;
        int col = (f4 & 127) * 4;
        ushort4 h2 = *(const ushort4*)((const char*)h2r + rowg * 1024 + col * 2);
        ushort4 h1 = *(const ushort4*)((const char*)C2 + rowg * 2048 + 1024 + col * 2);
        ushort4 hr = *(const ushort4*)((const char*)preb + rowg * 3072 + 1024 + col * 2);
        float4 pv = *(const float4*)(prev + rowg * 512 + col);
        float4 gc = *(const float4*)(g_c + col), bc = *(const float4*)(b_c + col);
        float4 gh = *(const float4*)(g_h + col), bh = *(const float4*)(b_h + col);
        float4 gp = *(const float4*)(g_pre + 512 + col);
        float4 bp = *(const float4*)(b_pre + 512 + col);
        float2 sc = shc[row], sh = shh[row], sp = st_p[rowg];
        auto fuse = [&](unsigned short h2u, unsigned short h1u, unsigned short hru,
                        float pvv, float gcv, float bcv, float ghv, float bhv,
                        float gpv, float bpv) -> float {
            float t2 = (bfu(h2u) - sc.x) * sc.y * gcv + bcv;
            float t1 = (bfu(h1u) - sh.x) * sh.y * ghv + bhv;
            float hg = sigmoid_fast((bfu(hru) - sp.x) * sp.y * gpv + bpv);
            return (1.f - hg) * tanh_fast(t1 + t2) + hg * pvv;
        };
        float4 o;
        o.x = fuse(h2.x, h1.x, hr.x, pv.x, gc.x, bc.x, gh.x, bh.x, gp.x, bp.x);
        o.y = fuse(h2.y, h1.y, hr.y, pv.y, gc.y, bc.y, gh.y, bh.y, gp.y, bp.y);
        o.z = fuse(h2.z, h1.z, hr.z, pv.z, gc.z, bc.z, gh.z, bh.z, gp.z, bp.z);
        o.w = fuse(h2.w, h1.w, hr.w, pv.w, gc.w, bc.w, gh.w, bh.w, gp.w, bp.w);
        *(float4*)(out + rowg * 512 + col) = o;
    }
}

// =============== small kernels ==============================================
// merged: prev->prevb and enc->encb in one launch
__global__ __launch_bounds__(256) void cvt4d(
    const float* __restrict__ a, __hip_bfloat16* __restrict__ ya,
    const float* __restrict__ b, __hip_bfloat16* __restrict__ yb)
{
    int i = blockIdx.x * 256 + threadIdx.x;     // 0..4194303
    const float* x; __hip_bfloat16* y; int k;
    if (i < 2097152) { x = a; y = ya; k = i; }
    else { x = b; y = yb; k = i - 2097152; }
    float4 v = ((const float4*)x)[k];
    bfx4 o;
    o.x = __float2bfloat16(v.x); o.y = __float2bfloat16(v.y);
    o.z = __float2bfloat16(v.z); o.w = __float2bfloat16(v.w);
    ((bfx4*)y)[k] = o;
}

__global__ __launch_bounds__(256) void wtrans(
    const float* __restrict__ w0, const float* __restrict__ w1,
    const float* __restrict__ w2, const float* __restrict__ w3,
    const float* __restrict__ w4, __hip_bfloat16* __restrict__ WT,
    __hip_bfloat16* __restrict__ WE2)
{
    int z = blockIdx.z;
    const float* W; __hip_bfloat16* O; int N;
    if (z == 0)      { W = w0; O = WT;                          N = 1536; }
    else if (z == 1) { W = w1; O = WE2;                         N = 512; }
    else if (z == 2) { W = w2; O = WT + 786432 + 262144;        N = 512; }
    else if (z == 3) { W = w3; O = WT + 786432 + 524288;        N = 512; }
    else             { W = w4; O = WT + 786432 + 786432;        N = 512; }
    int n0 = blockIdx.x * 32, k0 = blockIdx.y * 32;
    if (n0 >= N) return;
    __shared__ float t[32][33];
    int tx = threadIdx.x & 31, ty = threadIdx.x >> 5;
#pragma unroll
    for (int i = 0; i < 4; i++)
        t[ty + i * 8][tx] = W[(long)(k0 + ty + i * 8) * N + n0 + tx];
    __syncthreads();
#pragma unroll
    for (int i = 0; i < 4; i++)
        O[(long)(n0 + ty + i * 8) * 512 + k0 + tx] =
            __float2bfloat16(t[tx][ty + i * 8]);
}

// merged setup: wgscale (1024 blk) + cvt4(W_enc) (256 blk) + uvk (2 blk)
__global__ __launch_bounds__(256) void wprep(
    const __hip_bfloat16* __restrict__ wctxT, const float* __restrict__ g,
    __hip_bfloat16* __restrict__ wgT,
    const float* __restrict__ Wenc, __hip_bfloat16* __restrict__ wencb,
    const float* __restrict__ Wctx, const float* __restrict__ bvec,
    float* __restrict__ uv)
{
    const int bid = blockIdx.x;
    if (bid < 1024) {          // wgscale
        int i = bid * 256 + threadIdx.x;
        int d1 = i & 511;
        wgT[i] = __float2bfloat16(__bfloat162float(wctxT[i]) * g[d1]);
    } else if (bid < 1280) {   // cvt4 W_enc
        int i = (bid - 1024) * 256 + threadIdx.x;
        float4 v = ((const float4*)Wenc)[i];
        bfx4 o;
        o.x = __float2bfloat16(v.x); o.y = __float2bfloat16(v.y);
        o.z = __float2bfloat16(v.z); o.w = __float2bfloat16(v.w);
        ((bfx4*)wencb)[i] = o;
    } else {                   // uvk
        int d = (bid - 1280) * 256 + threadIdx.x;
        float u = 0.f, v = 0.f;
        for (int k = 0; k < 512; k++) {
            float w = Wctx[(long)k * 512 + d];
            u += g[k] * w; v += bvec[k] * w;
        }
        uv[d] = u; uv[512 + d] = v;
    }
}

__global__ __launch_bounds__(256) void stats_fin(
    const float2* __restrict__ part, float2* __restrict__ stats)
{
    int r = blockIdx.x * 256 + threadIdx.x;
    float s = 0.f, qq = 0.f;
#pragma unroll
    for (int cb = 0; cb < 12; cb++) {
        float2 v = part[(long)cb * 16384 + r]; s += v.x; qq += v.y;
    }
    float m = s * (1.f / 1536);
    float rs = rsqrtf(qq * (1.f / 1536) - m * m + LN_EPS);
    stats[r] = make_float2(m, rs);
}

__global__ __launch_bounds__(256) void scan_part2(
    const float* __restrict__ Ap, const float* __restrict__ Bp,
    const float* __restrict__ h0, float* __restrict__ sin_,
    float* __restrict__ hlast)
{
    int idx = blockIdx.x * 256 + threadIdx.x;
    float s = h0[idx];
    for (int ch = 0; ch < NCH; ch++) {
        sin_[ch * 16384 + idx] = s;
        s = Ap[ch * 16384 + idx] * s + Bp[ch * 16384 + idx];
    }
    hlast[idx] = s;
}

extern "C" void kernel_launch(void* const* d_in, const int* in_sizes, int n_in,
                              void* d_out, int out_size, void* d_ws, size_t ws_size,
                              hipStream_t stream) {
    const float* prev  = (const float*)d_in[0];
    const float* hid0  = (const float*)d_in[1];
    const float* enc   = (const float*)d_in[2];
    const int*   mlen  = (const int*)  d_in[3];
    const float* W_in  = (const float*)d_in[4];
    const float* W_enc = (const float*)d_in[5];
    const float* W_att = (const float*)d_in[6];
    const float* W_hid = (const float*)d_in[7];
    const float* W_ctx = (const float*)d_in[8];
    const float* g_pre = (const float*)d_in[9];
    const float* b_pre = (const float*)d_in[10];
    const float* g_enc = (const float*)d_in[11];
    const float* b_enc = (const float*)d_in[12];
    const float* g_att = (const float*)d_in[13];
    const float* b_att = (const float*)d_in[14];
    const float* g_h   = (const float*)d_in[15];
    const float* b_h   = (const float*)d_in[16];
    const float* g_c   = (const float*)d_in[17];
    const float* b_c   = (const float*)d_in[18];

    float* out   = (float*)d_out;                 // [T,B,D]
    float* hlast = out + (long)T_ * B_ * D_;      // [B,D]
    float* pattn = hlast + (long)B_ * D_;         // [T,B,S]

    char* ws = (char*)d_ws;
    __hip_bfloat16* preb    = (__hip_bfloat16*)(ws);               // 48MB
    __hip_bfloat16* WT      = (__hip_bfloat16*)(ws + 50331648);    // 4MB
    __hip_bfloat16* prevb   = (__hip_bfloat16*)(ws + 54525952);    // 16MB
    __hip_bfloat16* encb    = (__hip_bfloat16*)(ws + 71303168);    // 16MB
    __hip_bfloat16* pctxb   = (__hip_bfloat16*)(ws + 88080384);    // 16MB (LN'd)
    __hip_bfloat16* pwT     = (__hip_bfloat16*)(ws + 104857600);   // 16MB
    __hip_bfloat16* ssb     = (__hip_bfloat16*)(ws + 121634816);   // 16MB
    __hip_bfloat16* C2      = (__hip_bfloat16*)(ws + 138412032);   // 32MB [16384][1024]
    __hip_bfloat16* E2      = (__hip_bfloat16*)(ws + 171966464);   // 32MB [16384][1024]
    __hip_bfloat16* softb   = (__hip_bfloat16*)(ws + 171966464);   // 16MB (E2 lo, dead)
    __hip_bfloat16* h2raw   = (__hip_bfloat16*)(ws + 188743680);   // 16MB (E2 hi, dead)
    float2* part            = (float2*)(ws + 205520896);           // 2MB = 16 panels
    float2* stats           = (float2*)(ws + 207618048);           // 128KB
    float* scanA            = (float*)(ws + 207749120);            // 1MB
    float* scanB            = (float*)(ws + 208797696);            // 1MB
    float* sinb             = (float*)(ws + 209846272);            // 1MB
    __hip_bfloat16* WE2     = (__hip_bfloat16*)(ws + 211419136);   // 1MB [1024][512]
    float* uv               = (float*)(ws + 212467712);            // 4KB
    // setup-phase aliases (dead before scan kernels write them):
    __hip_bfloat16* WgT     = (__hip_bfloat16*)scanA;              // 0.5MB
    __hip_bfloat16* Wencbf  = (__hip_bfloat16*)scanB;              // 0.5MB

    float2* partA = part;                 // E2 panels (0-3 = pctx stats)
    float2* partB = part + 8 * 16384;     // C2 panels (0-3 att | 4-7 h1)
    float2* partC = part;                 // P-GEMM panels (reuse, partA dead)

    const __hip_bfloat16* W_attT = WT + 786432 + 262144;  // [W_att|W_hid] N=1024
    const __hip_bfloat16* W_ctxT = WT + 786432 + 786432;

    dim3 blk(256);

    // ---- setup ----
    cvt4d<<<16384, blk, 0, stream>>>(prev, prevb, enc, encb);
    wtrans<<<dim3(48, 16, 5), blk, 0, stream>>>(W_in, W_enc, W_att, W_hid,
                                                W_ctx, WT, WE2);
    wprep<<<1282, blk, 0, stream>>>(W_ctxT, g_enc, WgT, W_enc, Wencbf,
                                    W_ctx, b_enc, uv);
    g128<<<dim3(4, 4), blk, 0, stream>>>(WgT, 512, Wencbf, 0, WE2 + 262144,
                                         1024, nullptr, 1.f, 0);

    // ---- K1: preact GEMM -> preb bf16 + LN partials (12 panels) ----
    g128<<<dim3(12, 128), blk, 0, stream>>>(prevb, 512, WT, 0, preb, 3072,
                                            part, 1.f, 1);
    stats_fin<<<64, blk, 0, stream>>>(part, stats);

    // ---- merged: scan_part1 (512) + E2 GEMM (1024) ----
    g128e2s<<<1536, blk, 0, stream>>>(encb, WE2, E2, partA, preb, stats,
                                      g_pre, b_pre, scanA, scanB);
    scan_part2<<<64, blk, 0, stream>>>(scanA, scanB, hid0, sinb, hlast);

    // ---- merged: scan_part3 (512) + midfix (8192) ----
    mfix3<<<8704, blk, 0, stream>>>(preb, stats, g_pre, b_pre, sinb, ssb,
                                    E2, pctxb, pwT, partA, g_enc, b_enc, uv);

    // ---- C2 = ss @ [W_att|W_hid] (raw) + partials ----
    g128<<<dim3(8, 128), blk, 0, stream>>>(ssb, 512, W_attT, 0, C2, 2048,
                                           partB, 1.f, 1);

    // ---- K4: align + masked softmax (64-row blocks, shared B staging) ----
    gemm_attn<<<dim3(1, 8, 32), dim3(512), 0, stream>>>(C2, pctxb, partB,
                                                        g_att, b_att, mlen,
                                                        pattn, softb);

    // ---- h2 = P @ pwT / sqrt(d) + partials (XCD batch swizzle) ----
    g128<<<dim3(4, 4, 32), blk, 0, stream>>>(softb, 16384, pwT, 262144,
                                             h2raw, 32768, partC, RSQRT_D, 0);

    // ---- final fuse (inline stats c,h) ----
    fin_ep<<<512, blk, 0, stream>>>(h2raw, C2, preb, partC,
                                    partB + 4 * 16384, stats,
                                    g_c, b_c, g_h, b_h, g_pre, b_pre, prev,
                                    out);
}